// Round 11
// baseline (6913.704 us; speedup 1.0000x reference)
//
#include <hip/hip_runtime.h>
#include <math.h>

#define B_  64
#define T_  50
#define S_  50
#define U_  1024
#define E_  100
#define V_  30001
#define U4_ 4096
#define VP_ 30080   // V padded to a multiple of 128 for bf16 staging alignment

typedef __bf16 bf16_t;
typedef bf16_t bf16x8 __attribute__((ext_vector_type(8)));
typedef float  f32x4  __attribute__((ext_vector_type(4)));

// ---------------------------------------------------------------------------
// Coherence-point accessors. SYSTEM-scope atomics emit sc0+sc1 ops on gfx950:
// they bypass L1/L2 and read/write the L3 coherence point directly. (AGENT
// relaxed — r5's failure — only bypasses L1 and can hit a stale per-XCD L2.)
// Used ONLY for cross-block communicated data: hcprev, zp, flags. Everything
// read-only keeps plain cached loads and stays L2-resident (no fences ever).
// ---------------------------------------------------------------------------
__device__ __forceinline__ float scload(const float* p) {
    return __hip_atomic_load(p, __ATOMIC_RELAXED, __HIP_MEMORY_SCOPE_SYSTEM);
}
__device__ __forceinline__ void scstore(float* p, float v) {
    __hip_atomic_store(p, v, __ATOMIC_RELAXED, __HIP_MEMORY_SCOPE_SYSTEM);
}
__device__ __forceinline__ unsigned scload_u(const unsigned* p) {
    return __hip_atomic_load(p, __ATOMIC_RELAXED, __HIP_MEMORY_SCOPE_SYSTEM);
}
__device__ __forceinline__ void scadd_u(unsigned* p) {
    __hip_atomic_fetch_add(p, 1u, __ATOMIC_RELAXED, __HIP_MEMORY_SCOPE_SYSTEM);
}
__device__ __forceinline__ void scstore4(float* p, f32x4 v) {
    asm volatile("global_store_dwordx4 %0, %1, off sc0 sc1"
                 :: "v"(p), "v"(v) : "memory");
}
// all my outstanding vector-memory ops have completed (stores acked at L3)
__device__ __forceinline__ void vm_drain() {
    asm volatile("s_waitcnt vmcnt(0)" ::: "memory");
}
__device__ __forceinline__ void cbar() { asm volatile("" ::: "memory"); }

// ---------------------------------------------------------------------------
// Generic tiled f32 GEMM: C[M,N] = A[M,K] @ B[K,N] (+ bias).
// ---------------------------------------------------------------------------
__global__ __launch_bounds__(256) void gemm128(
    const float* __restrict__ A, int lda,
    const float* __restrict__ Bm, int ldb,
    float* __restrict__ C, int ldc,
    int N, int K, const float* __restrict__ bias)
{
    __shared__ float As[8][132];
    __shared__ float Bs[8][132];

    const int n0  = blockIdx.x * 128;
    const int m0  = blockIdx.y * 128;
    const int tid = threadIdx.x;
    const int tx  = tid & 15, ty = tid >> 4;

    float acc[8][8];
#pragma unroll
    for (int i = 0; i < 8; ++i)
#pragma unroll
        for (int j = 0; j < 8; ++j) acc[i][j] = 0.f;

    const int ra = tid >> 1, ca = (tid & 1) * 4;
    const int rb = tid >> 5, cb = (tid & 31) * 4;
    const bool fast_b = ((ldb & 3) == 0) && (n0 + 128 <= N);

    for (int k0 = 0; k0 < K; k0 += 8) {
        const float* ap = &A[(size_t)(m0 + ra) * lda + k0 + ca];
        float4 av;
        if (k0 + 8 <= K) {
            av = *(const float4*)ap;
        } else {
            av.x = (k0 + ca + 0 < K) ? ap[0] : 0.f;
            av.y = (k0 + ca + 1 < K) ? ap[1] : 0.f;
            av.z = (k0 + ca + 2 < K) ? ap[2] : 0.f;
            av.w = (k0 + ca + 3 < K) ? ap[3] : 0.f;
        }
        As[ca + 0][ra] = av.x;
        As[ca + 1][ra] = av.y;
        As[ca + 2][ra] = av.z;
        As[ca + 3][ra] = av.w;

        float4 bv = make_float4(0.f, 0.f, 0.f, 0.f);
        if (k0 + rb < K) {
            const float* bp = &Bm[(size_t)(k0 + rb) * ldb];
            if (fast_b) {
                bv = *(const float4*)&bp[n0 + cb];
            } else {
                bv.x = (n0 + cb + 0 < N) ? bp[n0 + cb + 0] : 0.f;
                bv.y = (n0 + cb + 1 < N) ? bp[n0 + cb + 1] : 0.f;
                bv.z = (n0 + cb + 2 < N) ? bp[n0 + cb + 2] : 0.f;
                bv.w = (n0 + cb + 3 < N) ? bp[n0 + cb + 3] : 0.f;
            }
        }
        *(float4*)&Bs[rb][cb] = bv;
        __syncthreads();

#pragma unroll
        for (int kk = 0; kk < 8; ++kk) {
            float4 a0 = *(const float4*)&As[kk][ty * 4];
            float4 a1 = *(const float4*)&As[kk][64 + ty * 4];
            float4 b0 = *(const float4*)&Bs[kk][tx * 4];
            float4 b1 = *(const float4*)&Bs[kk][64 + tx * 4];
            float a_[8] = {a0.x, a0.y, a0.z, a0.w, a1.x, a1.y, a1.z, a1.w};
            float b_[8] = {b0.x, b0.y, b0.z, b0.w, b1.x, b1.y, b1.z, b1.w};
#pragma unroll
            for (int i = 0; i < 8; ++i)
#pragma unroll
                for (int j = 0; j < 8; ++j)
                    acc[i][j] = fmaf(a_[i], b_[j], acc[i][j]);
        }
        __syncthreads();
    }

#pragma unroll
    for (int i = 0; i < 8; ++i) {
        int row = m0 + ((i < 4) ? (ty * 4 + i) : (64 + ty * 4 + (i - 4)));
#pragma unroll
        for (int j = 0; j < 8; ++j) {
            int col = n0 + ((j < 4) ? (tx * 4 + j) : (64 + tx * 4 + (j - 4)));
            if (col < N) {
                float v = acc[i][j];
                if (bias) v += bias[col];
                C[(size_t)row * ldc + col] = v;
            }
        }
    }
}

__global__ void add_inplace(float* __restrict__ dst, const float* __restrict__ src, int n)
{
    int i = blockIdx.x * blockDim.x + threadIdx.x;
    if (i < n) dst[i] += src[i];
}

__global__ void gather_emb(const int* __restrict__ tokens,
                           const float* __restrict__ emb,
                           float* __restrict__ xe)
{
    const int r = blockIdx.x;
    const int e = threadIdx.x;
    if (e < E_) xe[(size_t)r * E_ + e] = emb[(size_t)tokens[r] * E_ + e];
}

__global__ void cast_bf16(const float* __restrict__ src, bf16_t* __restrict__ dst, int n)
{
    int i = blockIdx.x * blockDim.x + threadIdx.x;
    const int stride = gridDim.x * blockDim.x;
    for (; i < n; i += stride) dst[i] = (bf16_t)src[i];
}

__global__ void cast_wo_bf16(const float* __restrict__ wo, bf16_t* __restrict__ dst)
{
    const int col = blockIdx.x * 256 + threadIdx.x;
    const int k   = blockIdx.y;
    if (col < VP_)
        dst[(size_t)k * VP_ + col] =
            (col < V_) ? (bf16_t)wo[(size_t)k * V_ + col] : (bf16_t)0.f;
}

// ---------------------------------------------------------------------------
// Split-K GEMM for t=0: zp[(ks*64+b)*4096+n] = sum_{k in slice} h0[b][k]*Uh[k][n]
// ---------------------------------------------------------------------------
__global__ __launch_bounds__(256) void zgemm_partial(
    const float* __restrict__ A, int lda,
    const float* __restrict__ Bm,
    float* __restrict__ zp)
{
    __shared__ float As[64][17];
    __shared__ float Bs[16][68];

    const int n0     = blockIdx.x * 64;
    const int ks     = blockIdx.y;
    const int k_base = ks * 256;
    const int tid    = threadIdx.x;
    const int tx     = tid & 15, ty = tid >> 4;

    float acc[4][4];
#pragma unroll
    for (int i = 0; i < 4; ++i)
#pragma unroll
        for (int j = 0; j < 4; ++j) acc[i][j] = 0.f;

    const int ra = tid >> 2, ca = (tid & 3) * 4;
    const int rb = tid >> 4, cb = (tid & 15) * 4;

    for (int kt = 0; kt < 16; ++kt) {
        const int k0 = k_base + kt * 16;
        float4 av = *(const float4*)&A[(size_t)ra * lda + k0 + ca];
        As[ra][ca + 0] = av.x;
        As[ra][ca + 1] = av.y;
        As[ra][ca + 2] = av.z;
        As[ra][ca + 3] = av.w;
        float4 bv = *(const float4*)&Bm[(size_t)(k0 + rb) * U4_ + n0 + cb];
        *(float4*)&Bs[rb][cb] = bv;
        __syncthreads();
#pragma unroll
        for (int kk = 0; kk < 16; ++kk) {
            float a_[4];
#pragma unroll
            for (int i = 0; i < 4; ++i) a_[i] = As[ty * 4 + i][kk];
            float4 bq = *(const float4*)&Bs[kk][tx * 4];
            float b_[4] = {bq.x, bq.y, bq.z, bq.w};
#pragma unroll
            for (int i = 0; i < 4; ++i)
#pragma unroll
                for (int j = 0; j < 4; ++j)
                    acc[i][j] = fmaf(a_[i], b_[j], acc[i][j]);
        }
        __syncthreads();
    }

#pragma unroll
    for (int i = 0; i < 4; ++i)
        *(float4*)&zp[((size_t)ks * 64 + ty * 4 + i) * U4_ + n0 + tx * 4] =
            make_float4(acc[i][0], acc[i][1], acc[i][2], acc[i][3]);
}

// ---------------------------------------------------------------------------
// Persistent decoder loop v6 — FENCELESS point-to-point flag pipeline.
// grid = 256 x 512. Block beta: ks = beta>>5 (K-slice), nt = beta&31.
// Cross-block data (hcprev, zp) moves via SYSTEM-scope sc0/sc1 ops (L3
// coherence point). Read-only data (Wcomb in LDS; keys/memory/zemb plain
// cached loads) is never invalidated — no fences anywhere in the loop.
// Flags: flags[0] = zp-done (256/step), flags[32] = h-done (64/step),
//        flags[64] = ctx-done (64/step). Monotonic counters.
// Pipelining: A-blocks with ks<4 depend only on h (start during attention).
// ---------------------------------------------------------------------------
__global__ __launch_bounds__(512) void decoder_loop6(
    const float* __restrict__ zemb,   // [3200][4096] (in d_out)
    const float* __restrict__ Wcomb,  // [2048][4096]
    const float* __restrict__ keys,   // [64][50][1024]
    const float* __restrict__ memory, // [64][50][1024]
    const float* __restrict__ c0,
    float* __restrict__ hcprev,       // [64][2048]   (sc-ops only)
    float* __restrict__ zp,           // [8][64][4096] (sc-ops only)
    float* __restrict__ hc_all,       // [64][50][2048] (plain; read post-loop)
    unsigned* flags)
{
    __shared__ float Bw[256 * 128];   // 128 KB persistent Wcomb slice
    __shared__ float As[2][32][68];
    __shared__ float hs[1024];
    __shared__ float sc[64];
    __shared__ float al[64];

    const int beta = blockIdx.x;
    const int tid  = threadIdx.x;

    const int nt = beta & 31, ks = beta >> 5;
    const int koff = ks * 256;
    const int c0c  = nt * 128;

    // ---- load persistent Wcomb slice into LDS (once) ----
    {
        const int k_sub = tid >> 5;
        const int c4    = (tid & 31) * 4;
#pragma unroll
        for (int it = 0; it < 16; ++it) {
            int k = it * 16 + k_sub;
            *(float4*)&Bw[k * 128 + c4] =
                *(const float4*)&Wcomb[(size_t)(koff + k) * U4_ + c0c + c4];
        }
    }

    const int b = beta;
    float creg[2] = {0.f, 0.f};
    if (beta < 64) {
        creg[0] = c0[b * U_ + tid];
        creg[1] = c0[b * U_ + tid + 512];
    }
    __syncthreads();

    // phase-A indices: 4x4 micro-tile, 64x32 staging chunks (4 floats/thread)
    const int tx   = tid & 31;
    const int ty   = tid >> 5;
    const int srow = tid >> 3;
    const int sk4  = (tid & 7) * 4;

    for (int t = 0; t < T_; ++t) {
        const int KS = t ? 8 : 4;

        // ---------------- phase A (t>=1): zp = hcprev-slice @ Bw ------------
        if (t) {
            // wait for producer of my k-slice: h (ks<4) or ctx (ks>=4)
            if (tid == 0) {
                const unsigned* f = (ks < 4) ? &flags[32] : &flags[64];
                const unsigned tgt = 64u * (unsigned)t;
                while (scload_u(f) < tgt) __builtin_amdgcn_s_sleep(1);
            }
            __syncthreads();
            cbar();

            float acc[4][4];
#pragma unroll
            for (int i = 0; i < 4; ++i)
#pragma unroll
                for (int j = 0; j < 4; ++j) acc[i][j] = 0.f;

            const float* ap = &hcprev[srow * 2048 + koff];
            float pf[4];
            {
                float s0 = scload(&ap[sk4 + 0]);
                float s1 = scload(&ap[sk4 + 1]);
                float s2 = scload(&ap[sk4 + 2]);
                float s3 = scload(&ap[sk4 + 3]);
                As[0][sk4 + 0][srow] = s0;
                As[0][sk4 + 1][srow] = s1;
                As[0][sk4 + 2][srow] = s2;
                As[0][sk4 + 3][srow] = s3;
#pragma unroll
                for (int j = 0; j < 4; ++j)
                    pf[j] = scload(&ap[32 + sk4 + j]);
            }
            __syncthreads();

            for (int kc = 0; kc < 8; ++kc) {
                const int cur = kc & 1;
                const float* bwp = &Bw[(kc * 32) * 128];
#pragma unroll
                for (int kk = 0; kk < 32; ++kk) {
                    float4 af = *(const float4*)&As[cur][kk][ty * 4];
                    float4 bf = *(const float4*)&bwp[kk * 128 + tx * 4];
                    float a_[4] = {af.x, af.y, af.z, af.w};
                    float b_[4] = {bf.x, bf.y, bf.z, bf.w};
#pragma unroll
                    for (int i = 0; i < 4; ++i)
#pragma unroll
                        for (int j = 0; j < 4; ++j)
                            acc[i][j] = fmaf(a_[i], b_[j], acc[i][j]);
                }
                if (kc < 7) {
#pragma unroll
                    for (int j = 0; j < 4; ++j)
                        As[cur ^ 1][sk4 + j][srow] = pf[j];
                    if (kc < 6) {
#pragma unroll
                        for (int j = 0; j < 4; ++j)
                            pf[j] = scload(&ap[(kc + 2) * 32 + sk4 + j]);
                    }
                }
                __syncthreads();
            }
#pragma unroll
            for (int i = 0; i < 4; ++i) {
                int m = ty * 4 + i;
                f32x4 vv = {acc[i][0], acc[i][1], acc[i][2], acc[i][3]};
                scstore4(&zp[((size_t)ks * 64 + m) * U4_ + c0c + tx * 4], vv);
            }
            vm_drain();          // my stores acked at coherence point
            __syncthreads();     // whole block's stores done
            if (tid == 0) scadd_u(&flags[0]);
        }

        // ---------------- phase BC: gates + attention (blocks < 64) ---------
        if (beta < 64) {
            if (t) {
                if (tid == 0) {
                    const unsigned tgt = 256u * (unsigned)t;
                    while (scload_u(&flags[0]) < tgt) __builtin_amdgcn_s_sleep(1);
                }
                __syncthreads();
                cbar();
            }

            const float* ze = &zemb[((size_t)b * T_ + t) * U4_];
            float hn_[2];
#pragma unroll
            for (int i = 0; i < 2; ++i) {
                const int u = tid + 512 * i;
                float zg[4];
#pragma unroll
                for (int g = 0; g < 4; ++g) {
                    const int col = g * U_ + u;
                    float a = ze[col];
#pragma unroll
                    for (int s = 0; s < 8; ++s)
                        if (s < KS) a += scload(&zp[((size_t)s * 64 + b) * U4_ + col]);
                    zg[g] = a;
                }
                const float si = 1.f / (1.f + expf(-zg[0]));
                const float sf = 1.f / (1.f + expf(-zg[1]));
                const float tg = tanhf(zg[2]);
                const float so = 1.f / (1.f + expf(-zg[3]));
                const float cn = sf * creg[i] + si * tg;
                creg[i] = cn;
                const float hn = so * tanhf(cn);
                hn_[i] = hn;
                hs[u] = hn;
            }
            // publish h (sc) + archive (plain)
#pragma unroll
            for (int i = 0; i < 2; ++i) {
                const int u = tid + 512 * i;
                scstore(&hcprev[b * 2048 + u], hn_[i]);
                hc_all[((size_t)b * T_ + t) * 2048 + u] = hn_[i];
            }
            vm_drain();
            __syncthreads();                 // hs complete + h stores acked
            if (tid == 0) scadd_u(&flags[32]);

            // scores (keys: plain loads, L2-resident across steps)
            const int lane = tid & 63, w = tid >> 6;
            for (int s = w; s < S_; s += 8) {
                const float* kp = &keys[((size_t)b * S_ + s) * U_ + lane * 16];
                const float* hp = &hs[lane * 16];
                float p = 0.f;
#pragma unroll
                for (int q = 0; q < 4; ++q) {
                    float4 kv = *(const float4*)&kp[q * 4];
                    float4 hv = *(const float4*)&hp[q * 4];
                    p = fmaf(hv.x, kv.x, p);
                    p = fmaf(hv.y, kv.y, p);
                    p = fmaf(hv.z, kv.z, p);
                    p = fmaf(hv.w, kv.w, p);
                }
#pragma unroll
                for (int off = 32; off > 0; off >>= 1)
                    p += __shfl_xor(p, off);
                if (lane == 0) sc[s] = p;
            }
            __syncthreads();

            if (tid < 64) {
                float v = (tid < S_) ? sc[tid] : -INFINITY;
                float m = v;
#pragma unroll
                for (int off = 32; off > 0; off >>= 1)
                    m = fmaxf(m, __shfl_xor(m, off));
                float e = (tid < S_) ? expf(v - m) : 0.f;
                float ssum = e;
#pragma unroll
                for (int off = 32; off > 0; off >>= 1)
                    ssum += __shfl_xor(ssum, off);
                if (tid < S_) al[tid] = e / ssum;
            }
            __syncthreads();

            // ctx (memory: plain loads, L2-resident)
            {
                const float2* mp = (const float2*)&memory[(size_t)b * S_ * U_];
                float cx = 0.f, cy = 0.f;
#pragma unroll 10
                for (int s = 0; s < S_; ++s) {
                    float2 mv = mp[s * 512 + tid];
                    const float a = al[s];
                    cx = fmaf(a, mv.x, cx);
                    cy = fmaf(a, mv.y, cy);
                }
                scstore(&hcprev[b * 2048 + U_ + tid * 2 + 0], cx);
                scstore(&hcprev[b * 2048 + U_ + tid * 2 + 1], cy);
                hc_all[((size_t)b * T_ + t) * 2048 + U_ + tid * 2 + 0] = cx;
                hc_all[((size_t)b * T_ + t) * 2048 + U_ + tid * 2 + 1] = cy;
            }
            vm_drain();
            __syncthreads();
            if (tid == 0) scadd_u(&flags[64]);
        }
    }
}

// ---------------------------------------------------------------------------
// bf16 MFMA GEMM: C[3200][V] = A[3200][1024] @ B[1024][VP_] + bias.
// ---------------------------------------------------------------------------
__global__ __launch_bounds__(256) void gemm_wo_mfma(
    const bf16_t* __restrict__ A,
    const bf16_t* __restrict__ Bw,
    const float*  __restrict__ bias,
    float* __restrict__ C)
{
    __shared__ bf16_t As[128][40];
    __shared__ bf16_t Bs[128][40];

    const int n0  = blockIdx.x * 128;
    const int m0  = blockIdx.y * 128;
    const int tid = threadIdx.x;
    const int wave = tid >> 6, lane = tid & 63;
    const int wr = wave >> 1, wc = wave & 1;
    const int lr = lane & 15;
    const int lk = lane >> 4;

    f32x4 acc[4][4] = {};

    const int ar = tid >> 1;
    const int ak = (tid & 1) * 16;
    const int bk = tid >> 3;
    const int bn = (tid & 7) * 16;

    for (int k0 = 0; k0 < U_; k0 += 32) {
        {
            const bf16_t* ap = &A[(size_t)(m0 + ar) * U_ + k0 + ak];
            *(bf16x8*)&As[ar][ak]     = *(const bf16x8*)ap;
            *(bf16x8*)&As[ar][ak + 8] = *(const bf16x8*)(ap + 8);
        }
        {
            const bf16_t* bp = &Bw[(size_t)(k0 + bk) * VP_ + n0 + bn];
            bf16x8 v0 = *(const bf16x8*)bp;
            bf16x8 v1 = *(const bf16x8*)(bp + 8);
#pragma unroll
            for (int i = 0; i < 8; ++i) Bs[bn + i][bk] = v0[i];
#pragma unroll
            for (int i = 0; i < 8; ++i) Bs[bn + 8 + i][bk] = v1[i];
        }
        __syncthreads();

        bf16x8 af[4], bf[4];
#pragma unroll
        for (int m = 0; m < 4; ++m)
            af[m] = *(const bf16x8*)&As[wr * 64 + m * 16 + lr][lk * 8];
#pragma unroll
        for (int n = 0; n < 4; ++n)
            bf[n] = *(const bf16x8*)&Bs[wc * 64 + n * 16 + lr][lk * 8];
#pragma unroll
        for (int m = 0; m < 4; ++m)
#pragma unroll
            for (int n = 0; n < 4; ++n)
                acc[m][n] = __builtin_amdgcn_mfma_f32_16x16x32_bf16(
                    af[m], bf[n], acc[m][n], 0, 0, 0);
        __syncthreads();
    }

#pragma unroll
    for (int m = 0; m < 4; ++m) {
        const int row = m0 + wr * 64 + m * 16 + lk * 4;
#pragma unroll
        for (int n = 0; n < 4; ++n) {
            const int col = n0 + wc * 64 + n * 16 + lr;
            if (col < V_) {
                const float bb = bias[col];
#pragma unroll
                for (int r = 0; r < 4; ++r)
                    C[(size_t)(row + r) * V_ + col] = acc[m][n][r] + bb;
            }
        }
    }
}

// ---------------------------------------------------------------------------
extern "C" void kernel_launch(void* const* d_in, const int* in_sizes, int n_in,
                              void* d_out, int out_size, void* d_ws, size_t ws_size,
                              hipStream_t stream)
{
    const int*   tokens = (const int*)  d_in[0];
    const float* memory = (const float*)d_in[1];
    const float* h0     = (const float*)d_in[2];
    const float* c0     = (const float*)d_in[3];
    const float* emb    = (const float*)d_in[4];
    const float* Wx     = (const float*)d_in[5];
    const float* Uh     = (const float*)d_in[6];
    const float* bvec   = (const float*)d_in[7];
    const float* Wm     = (const float*)d_in[8];
    const float* Wa     = (const float*)d_in[9];
    const float* Wo     = (const float*)d_in[10];
    const float* bo     = (const float*)d_in[11];
    float* out = (float*)d_out;

    // ---- workspace layout (float units) ----
    float* ws = (float*)d_ws;
    size_t off = 0;
    float*   Wcomb  = ws + off; off += (size_t)2048 * U4_;      // 33.55 MB
    float*   keys   = ws + off; off += (size_t)B_ * S_ * U_;    // 13.11 MB
    float*   hc_all = ws + off; off += (size_t)B_ * T_ * 2048;  // 26.21 MB
    float*   zp     = ws + off; off += (size_t)8 * B_ * U4_;    //  8.39 MB
    float*   hcprev = ws + off; off += (size_t)B_ * 2048;       //  0.52 MB
    float*   x_emb  = ws + off; off += (size_t)B_ * T_ * E_;    //  1.28 MB
    unsigned* flags = (unsigned*)(ws + off); off += 256;        //  1 KB
    bf16_t*  wo_bf  = (bf16_t*)(ws + off); off += (size_t)1024 * VP_ / 2; // 61.6 MB
    const size_t need_bytes = off * sizeof(float);

    // d_out-resident scratch (dead before the final GEMM writes out)
    float* zemb = out;                             // [3200][4096] 52.4 MB
    // post-loop aliases (Wcomb dead after the loop)
    float*  attn_all = Wcomb;
    bf16_t* abf      = (bf16_t*)(Wcomb + (size_t)B_ * T_ * U_);

    const bool use_mfma = (ws_size >= need_bytes);

    (void)hipMemsetAsync(flags, 0, 256 * sizeof(unsigned), stream);

    // ---- pre-loop ----
    gather_emb<<<B_ * T_, 128, 0, stream>>>(tokens, emb, x_emb);
    gemm128<<<dim3(32, 25), 256, 0, stream>>>(
        x_emb, E_, Wx, U4_, zemb, U4_, U4_, E_, bvec);
    gemm128<<<dim3(32, 16), 256, 0, stream>>>(
        Wa, U_, Wx + (size_t)E_ * U4_, U4_, Wcomb, U4_, U4_, U_, nullptr);
    add_inplace<<<(1024 * U4_) / 256, 256, 0, stream>>>(Wcomb, Uh, 1024 * U4_);
    gemm128<<<dim3(8, 25), 256, 0, stream>>>(
        memory, U_, Wm, U_, keys, U_, U_, U_, nullptr);
    zgemm_partial<<<dim3(64, 4), 256, 0, stream>>>(h0, U_, Uh, zp);
    if (use_mfma)
        cast_wo_bf16<<<dim3((VP_ + 255) / 256, 1024), 256, 0, stream>>>(Wo, wo_bf);

    // ---- persistent recurrent loop (fenceless flag pipeline) ----
    decoder_loop6<<<256, 512, 0, stream>>>(
        zemb, Wcomb, keys, memory, c0, hcprev, zp, hc_all, flags);

    // ---- post-loop ----
    gemm128<<<dim3(8, 25), 256, 0, stream>>>(
        hc_all, 2048, Wa, U_, attn_all, U_, U_, 2048, nullptr);

    if (use_mfma) {
        cast_bf16<<<2048, 256, 0, stream>>>(attn_all, abf, B_ * T_ * U_);
        gemm_wo_mfma<<<dim3(VP_ / 128, 25), 256, 0, stream>>>(abf, wo_bf, bo, out);
    } else {
        gemm128<<<dim3(235, 25), 256, 0, stream>>>(
            attn_all, U_, Wo, V_, out, V_, V_, U_, bo);
    }
}

// Round 12
// 5145.673 us; speedup vs baseline: 1.3436x; 1.3436x over previous
//
#include <hip/hip_runtime.h>
#include <math.h>

#define B_  64
#define T_  50
#define S_  50
#define U_  1024
#define E_  100
#define V_  30001
#define U4_ 4096
#define VP_ 30080   // V padded to a multiple of 128 for bf16 staging alignment

typedef __bf16 bf16_t;
typedef bf16_t bf16x8 __attribute__((ext_vector_type(8)));
typedef float  f32x4  __attribute__((ext_vector_type(4)));
typedef unsigned long long u64_t;

// ---------------------------------------------------------------------------
// Coherence-point accessors (SYSTEM scope -> sc0+sc1, bypass L1/L2, proven
// correct in r11). This round: all loads/stores 8B-wide, lane-contiguous, so
// each wave transaction covers full cache lines (r11 regression was scalar
// sc accesses inflating EA traffic ~4-16x).
// ---------------------------------------------------------------------------
__device__ __forceinline__ float2 scload8(const float* p) {
    u64_t v = __hip_atomic_load((const u64_t*)p, __ATOMIC_RELAXED,
                                __HIP_MEMORY_SCOPE_SYSTEM);
    union { u64_t u; float2 f; } c; c.u = v; return c.f;
}
__device__ __forceinline__ void scstore8(float* p, float x, float y) {
    union { u64_t u; float2 f; } c; c.f = make_float2(x, y);
    __hip_atomic_store((u64_t*)p, c.u, __ATOMIC_RELAXED,
                       __HIP_MEMORY_SCOPE_SYSTEM);
}
__device__ __forceinline__ unsigned scload_u(const unsigned* p) {
    return __hip_atomic_load(p, __ATOMIC_RELAXED, __HIP_MEMORY_SCOPE_SYSTEM);
}
__device__ __forceinline__ void scadd_u(unsigned* p) {
    __hip_atomic_fetch_add(p, 1u, __ATOMIC_RELAXED, __HIP_MEMORY_SCOPE_SYSTEM);
}
__device__ __forceinline__ void scstore4(float* p, f32x4 v) {
    asm volatile("global_store_dwordx4 %0, %1, off sc0 sc1"
                 :: "v"(p), "v"(v) : "memory");
}
__device__ __forceinline__ void vm_drain() {
    asm volatile("s_waitcnt vmcnt(0)" ::: "memory");
}
__device__ __forceinline__ void cbar() { asm volatile("" ::: "memory"); }

// ---------------------------------------------------------------------------
// Generic tiled f32 GEMM: C[M,N] = A[M,K] @ B[K,N] (+ bias).
// ---------------------------------------------------------------------------
__global__ __launch_bounds__(256) void gemm128(
    const float* __restrict__ A, int lda,
    const float* __restrict__ Bm, int ldb,
    float* __restrict__ C, int ldc,
    int N, int K, const float* __restrict__ bias)
{
    __shared__ float As[8][132];
    __shared__ float Bs[8][132];

    const int n0  = blockIdx.x * 128;
    const int m0  = blockIdx.y * 128;
    const int tid = threadIdx.x;
    const int tx  = tid & 15, ty = tid >> 4;

    float acc[8][8];
#pragma unroll
    for (int i = 0; i < 8; ++i)
#pragma unroll
        for (int j = 0; j < 8; ++j) acc[i][j] = 0.f;

    const int ra = tid >> 1, ca = (tid & 1) * 4;
    const int rb = tid >> 5, cb = (tid & 31) * 4;
    const bool fast_b = ((ldb & 3) == 0) && (n0 + 128 <= N);

    for (int k0 = 0; k0 < K; k0 += 8) {
        const float* ap = &A[(size_t)(m0 + ra) * lda + k0 + ca];
        float4 av;
        if (k0 + 8 <= K) {
            av = *(const float4*)ap;
        } else {
            av.x = (k0 + ca + 0 < K) ? ap[0] : 0.f;
            av.y = (k0 + ca + 1 < K) ? ap[1] : 0.f;
            av.z = (k0 + ca + 2 < K) ? ap[2] : 0.f;
            av.w = (k0 + ca + 3 < K) ? ap[3] : 0.f;
        }
        As[ca + 0][ra] = av.x;
        As[ca + 1][ra] = av.y;
        As[ca + 2][ra] = av.z;
        As[ca + 3][ra] = av.w;

        float4 bv = make_float4(0.f, 0.f, 0.f, 0.f);
        if (k0 + rb < K) {
            const float* bp = &Bm[(size_t)(k0 + rb) * ldb];
            if (fast_b) {
                bv = *(const float4*)&bp[n0 + cb];
            } else {
                bv.x = (n0 + cb + 0 < N) ? bp[n0 + cb + 0] : 0.f;
                bv.y = (n0 + cb + 1 < N) ? bp[n0 + cb + 1] : 0.f;
                bv.z = (n0 + cb + 2 < N) ? bp[n0 + cb + 2] : 0.f;
                bv.w = (n0 + cb + 3 < N) ? bp[n0 + cb + 3] : 0.f;
            }
        }
        *(float4*)&Bs[rb][cb] = bv;
        __syncthreads();

#pragma unroll
        for (int kk = 0; kk < 8; ++kk) {
            float4 a0 = *(const float4*)&As[kk][ty * 4];
            float4 a1 = *(const float4*)&As[kk][64 + ty * 4];
            float4 b0 = *(const float4*)&Bs[kk][tx * 4];
            float4 b1 = *(const float4*)&Bs[kk][64 + tx * 4];
            float a_[8] = {a0.x, a0.y, a0.z, a0.w, a1.x, a1.y, a1.z, a1.w};
            float b_[8] = {b0.x, b0.y, b0.z, b0.w, b1.x, b1.y, b1.z, b1.w};
#pragma unroll
            for (int i = 0; i < 8; ++i)
#pragma unroll
                for (int j = 0; j < 8; ++j)
                    acc[i][j] = fmaf(a_[i], b_[j], acc[i][j]);
        }
        __syncthreads();
    }

#pragma unroll
    for (int i = 0; i < 8; ++i) {
        int row = m0 + ((i < 4) ? (ty * 4 + i) : (64 + ty * 4 + (i - 4)));
#pragma unroll
        for (int j = 0; j < 8; ++j) {
            int col = n0 + ((j < 4) ? (tx * 4 + j) : (64 + tx * 4 + (j - 4)));
            if (col < N) {
                float v = acc[i][j];
                if (bias) v += bias[col];
                C[(size_t)row * ldc + col] = v;
            }
        }
    }
}

__global__ void add_inplace(float* __restrict__ dst, const float* __restrict__ src, int n)
{
    int i = blockIdx.x * blockDim.x + threadIdx.x;
    if (i < n) dst[i] += src[i];
}

__global__ void gather_emb(const int* __restrict__ tokens,
                           const float* __restrict__ emb,
                           float* __restrict__ xe)
{
    const int r = blockIdx.x;
    const int e = threadIdx.x;
    if (e < E_) xe[(size_t)r * E_ + e] = emb[(size_t)tokens[r] * E_ + e];
}

__global__ void cast_bf16(const float* __restrict__ src, bf16_t* __restrict__ dst, int n)
{
    int i = blockIdx.x * blockDim.x + threadIdx.x;
    const int stride = gridDim.x * blockDim.x;
    for (; i < n; i += stride) dst[i] = (bf16_t)src[i];
}

__global__ void cast_wo_bf16(const float* __restrict__ wo, bf16_t* __restrict__ dst)
{
    const int col = blockIdx.x * 256 + threadIdx.x;
    const int k   = blockIdx.y;
    if (col < VP_)
        dst[(size_t)k * VP_ + col] =
            (col < V_) ? (bf16_t)wo[(size_t)k * V_ + col] : (bf16_t)0.f;
}

// ---------------------------------------------------------------------------
// Split-K GEMM for t=0: zp[(ks*64+b)*4096+n] = sum_{k in slice} h0[b][k]*Uh[k][n]
// ---------------------------------------------------------------------------
__global__ __launch_bounds__(256) void zgemm_partial(
    const float* __restrict__ A, int lda,
    const float* __restrict__ Bm,
    float* __restrict__ zp)
{
    __shared__ float As[64][17];
    __shared__ float Bs[16][68];

    const int n0     = blockIdx.x * 64;
    const int ks     = blockIdx.y;
    const int k_base = ks * 256;
    const int tid    = threadIdx.x;
    const int tx     = tid & 15, ty = tid >> 4;

    float acc[4][4];
#pragma unroll
    for (int i = 0; i < 4; ++i)
#pragma unroll
        for (int j = 0; j < 4; ++j) acc[i][j] = 0.f;

    const int ra = tid >> 2, ca = (tid & 3) * 4;
    const int rb = tid >> 4, cb = (tid & 15) * 4;

    for (int kt = 0; kt < 16; ++kt) {
        const int k0 = k_base + kt * 16;
        float4 av = *(const float4*)&A[(size_t)ra * lda + k0 + ca];
        As[ra][ca + 0] = av.x;
        As[ra][ca + 1] = av.y;
        As[ra][ca + 2] = av.z;
        As[ra][ca + 3] = av.w;
        float4 bv = *(const float4*)&Bm[(size_t)(k0 + rb) * U4_ + n0 + cb];
        *(float4*)&Bs[rb][cb] = bv;
        __syncthreads();
#pragma unroll
        for (int kk = 0; kk < 16; ++kk) {
            float a_[4];
#pragma unroll
            for (int i = 0; i < 4; ++i) a_[i] = As[ty * 4 + i][kk];
            float4 bq = *(const float4*)&Bs[kk][tx * 4];
            float b_[4] = {bq.x, bq.y, bq.z, bq.w};
#pragma unroll
            for (int i = 0; i < 4; ++i)
#pragma unroll
                for (int j = 0; j < 4; ++j)
                    acc[i][j] = fmaf(a_[i], b_[j], acc[i][j]);
        }
        __syncthreads();
    }

#pragma unroll
    for (int i = 0; i < 4; ++i)
        *(float4*)&zp[((size_t)ks * 64 + ty * 4 + i) * U4_ + n0 + tx * 4] =
            make_float4(acc[i][0], acc[i][1], acc[i][2], acc[i][3]);
}

// ---------------------------------------------------------------------------
// Persistent decoder loop v7 — fenceless flag pipeline (r11 structure, proven
// correct) with ALL sc accesses vectorized to 8B lane-contiguous.
// grid = 256 x 512. Block beta: ks = beta>>5, nt = beta&31.
// Flags: flags[0]=zp-done(256/step), flags[32]=h-done(64), flags[64]=ctx-done(64).
// ---------------------------------------------------------------------------
__global__ __launch_bounds__(512) void decoder_loop7(
    const float* __restrict__ zemb,   // [3200][4096] (in d_out)
    const float* __restrict__ Wcomb,  // [2048][4096]
    const float* __restrict__ keys,   // [64][50][1024]
    const float* __restrict__ memory, // [64][50][1024]
    const float* __restrict__ c0,
    float* __restrict__ hcprev,       // [64][2048]   (sc-ops only)
    float* __restrict__ zp,           // [8][64][4096] (sc-ops only)
    float* __restrict__ hc_all,       // [64][50][2048] (plain)
    unsigned* flags)
{
    __shared__ float Bw[256 * 128];   // 128 KB persistent Wcomb slice
    __shared__ float As[2][32][68];
    __shared__ float hs[1024];
    __shared__ float sc[64];
    __shared__ float al[64];

    const int beta = blockIdx.x;
    const int tid  = threadIdx.x;

    const int nt = beta & 31, ks = beta >> 5;
    const int koff = ks * 256;
    const int c0c  = nt * 128;

    // ---- load persistent Wcomb slice into LDS (once) ----
    {
        const int k_sub = tid >> 5;
        const int c4    = (tid & 31) * 4;
#pragma unroll
        for (int it = 0; it < 16; ++it) {
            int k = it * 16 + k_sub;
            *(float4*)&Bw[k * 128 + c4] =
                *(const float4*)&Wcomb[(size_t)(koff + k) * U4_ + c0c + c4];
        }
    }

    const int b  = beta;
    const int u2 = tid * 2;           // BC thread owns u = {u2, u2+1}
    float creg[2] = {0.f, 0.f};
    if (beta < 64) {
        float2 cv = *(const float2*)&c0[b * U_ + u2];
        creg[0] = cv.x;
        creg[1] = cv.y;
    }
    __syncthreads();

    // phase-A indices
    const int tx   = tid & 31;
    const int ty   = tid >> 5;
    const int srow = tid >> 3;
    const int sk4  = (tid & 7) * 4;

    for (int t = 0; t < T_; ++t) {
        const int KS = t ? 8 : 4;

        // ---------------- phase A (t>=1): zp = hcprev-slice @ Bw ------------
        if (t) {
            if (tid == 0) {
                const unsigned* f = (ks < 4) ? &flags[32] : &flags[64];
                const unsigned tgt = 64u * (unsigned)t;
                while (scload_u(f) < tgt) __builtin_amdgcn_s_sleep(1);
            }
            __syncthreads();
            cbar();

            float acc[4][4];
#pragma unroll
            for (int i = 0; i < 4; ++i)
#pragma unroll
                for (int j = 0; j < 4; ++j) acc[i][j] = 0.f;

            const float* ap = &hcprev[srow * 2048 + koff];
            float2 pf0, pf1;
            {
                float2 s0 = scload8(&ap[sk4]);
                float2 s1 = scload8(&ap[sk4 + 2]);
                As[0][sk4 + 0][srow] = s0.x;
                As[0][sk4 + 1][srow] = s0.y;
                As[0][sk4 + 2][srow] = s1.x;
                As[0][sk4 + 3][srow] = s1.y;
                pf0 = scload8(&ap[32 + sk4]);
                pf1 = scload8(&ap[32 + sk4 + 2]);
            }
            __syncthreads();

            for (int kc = 0; kc < 8; ++kc) {
                const int cur = kc & 1;
                const float* bwp = &Bw[(kc * 32) * 128];
#pragma unroll
                for (int kk = 0; kk < 32; ++kk) {
                    float4 af = *(const float4*)&As[cur][kk][ty * 4];
                    float4 bf = *(const float4*)&bwp[kk * 128 + tx * 4];
                    float a_[4] = {af.x, af.y, af.z, af.w};
                    float b_[4] = {bf.x, bf.y, bf.z, bf.w};
#pragma unroll
                    for (int i = 0; i < 4; ++i)
#pragma unroll
                        for (int j = 0; j < 4; ++j)
                            acc[i][j] = fmaf(a_[i], b_[j], acc[i][j]);
                }
                if (kc < 7) {
                    As[cur ^ 1][sk4 + 0][srow] = pf0.x;
                    As[cur ^ 1][sk4 + 1][srow] = pf0.y;
                    As[cur ^ 1][sk4 + 2][srow] = pf1.x;
                    As[cur ^ 1][sk4 + 3][srow] = pf1.y;
                    if (kc < 6) {
                        pf0 = scload8(&ap[(kc + 2) * 32 + sk4]);
                        pf1 = scload8(&ap[(kc + 2) * 32 + sk4 + 2]);
                    }
                }
                __syncthreads();
            }
#pragma unroll
            for (int i = 0; i < 4; ++i) {
                int m = ty * 4 + i;
                f32x4 vv = {acc[i][0], acc[i][1], acc[i][2], acc[i][3]};
                scstore4(&zp[((size_t)ks * 64 + m) * U4_ + c0c + tx * 4], vv);
            }
            vm_drain();
            __syncthreads();
            if (tid == 0) scadd_u(&flags[0]);
        }

        // ---------------- phase BC: gates + attention (blocks < 64) ---------
        if (beta < 64) {
            if (t) {
                if (tid == 0) {
                    const unsigned tgt = 256u * (unsigned)t;
                    while (scload_u(&flags[0]) < tgt) __builtin_amdgcn_s_sleep(1);
                }
                __syncthreads();
                cbar();
            }

            const float* ze = &zemb[((size_t)b * T_ + t) * U4_];
            float zgx[4], zgy[4];
#pragma unroll
            for (int g = 0; g < 4; ++g) {
                float2 a = *(const float2*)&ze[g * U_ + u2];  // plain cached
                zgx[g] = a.x;
                zgy[g] = a.y;
            }
#pragma unroll
            for (int s = 0; s < 8; ++s)
                if (s < KS) {
#pragma unroll
                    for (int g = 0; g < 4; ++g) {
                        float2 v = scload8(&zp[((size_t)s * 64 + b) * U4_ + g * U_ + u2]);
                        zgx[g] += v.x;
                        zgy[g] += v.y;
                    }
                }

            const float six = 1.f / (1.f + expf(-zgx[0]));
            const float sfx = 1.f / (1.f + expf(-zgx[1]));
            const float tgx = tanhf(zgx[2]);
            const float sox = 1.f / (1.f + expf(-zgx[3]));
            const float cnx = sfx * creg[0] + six * tgx;
            creg[0] = cnx;
            const float hnx = sox * tanhf(cnx);

            const float siy = 1.f / (1.f + expf(-zgy[0]));
            const float sfy = 1.f / (1.f + expf(-zgy[1]));
            const float tgy = tanhf(zgy[2]);
            const float soy = 1.f / (1.f + expf(-zgy[3]));
            const float cny = sfy * creg[1] + siy * tgy;
            creg[1] = cny;
            const float hny = soy * tanhf(cny);

            hs[u2]     = hnx;
            hs[u2 + 1] = hny;
            scstore8(&hcprev[b * 2048 + u2], hnx, hny);
            *(float2*)&hc_all[((size_t)b * T_ + t) * 2048 + u2] =
                make_float2(hnx, hny);
            vm_drain();
            __syncthreads();
            if (tid == 0) scadd_u(&flags[32]);

            // scores (keys plain cached, L2-resident — no fences ever)
            const int lane = tid & 63, w = tid >> 6;
            for (int s = w; s < S_; s += 8) {
                const float* kp = &keys[((size_t)b * S_ + s) * U_ + lane * 16];
                const float* hp = &hs[lane * 16];
                float p = 0.f;
#pragma unroll
                for (int q = 0; q < 4; ++q) {
                    float4 kv = *(const float4*)&kp[q * 4];
                    float4 hv = *(const float4*)&hp[q * 4];
                    p = fmaf(hv.x, kv.x, p);
                    p = fmaf(hv.y, kv.y, p);
                    p = fmaf(hv.z, kv.z, p);
                    p = fmaf(hv.w, kv.w, p);
                }
#pragma unroll
                for (int off = 32; off > 0; off >>= 1)
                    p += __shfl_xor(p, off);
                if (lane == 0) sc[s] = p;
            }
            __syncthreads();

            if (tid < 64) {
                float v = (tid < S_) ? sc[tid] : -INFINITY;
                float m = v;
#pragma unroll
                for (int off = 32; off > 0; off >>= 1)
                    m = fmaxf(m, __shfl_xor(m, off));
                float e = (tid < S_) ? expf(v - m) : 0.f;
                float ssum = e;
#pragma unroll
                for (int off = 32; off > 0; off >>= 1)
                    ssum += __shfl_xor(ssum, off);
                if (tid < S_) al[tid] = e / ssum;
            }
            __syncthreads();

            // ctx (memory plain cached, L2-resident)
            {
                const float2* mp = (const float2*)&memory[(size_t)b * S_ * U_];
                float cx = 0.f, cy = 0.f;
#pragma unroll 10
                for (int s = 0; s < S_; ++s) {
                    float2 mv = mp[s * 512 + tid];
                    const float a = al[s];
                    cx = fmaf(a, mv.x, cx);
                    cy = fmaf(a, mv.y, cy);
                }
                scstore8(&hcprev[b * 2048 + U_ + u2], cx, cy);
                *(float2*)&hc_all[((size_t)b * T_ + t) * 2048 + U_ + u2] =
                    make_float2(cx, cy);
            }
            vm_drain();
            __syncthreads();
            if (tid == 0) scadd_u(&flags[64]);
        }
    }
}

// ---------------------------------------------------------------------------
// bf16 MFMA GEMM: C[3200][V] = A[3200][1024] @ B[1024][VP_] + bias.
// ---------------------------------------------------------------------------
__global__ __launch_bounds__(256) void gemm_wo_mfma(
    const bf16_t* __restrict__ A,
    const bf16_t* __restrict__ Bw,
    const float*  __restrict__ bias,
    float* __restrict__ C)
{
    __shared__ bf16_t As[128][40];
    __shared__ bf16_t Bs[128][40];

    const int n0  = blockIdx.x * 128;
    const int m0  = blockIdx.y * 128;
    const int tid = threadIdx.x;
    const int wave = tid >> 6, lane = tid & 63;
    const int wr = wave >> 1, wc = wave & 1;
    const int lr = lane & 15;
    const int lk = lane >> 4;

    f32x4 acc[4][4] = {};

    const int ar = tid >> 1;
    const int ak = (tid & 1) * 16;
    const int bk = tid >> 3;
    const int bn = (tid & 7) * 16;

    for (int k0 = 0; k0 < U_; k0 += 32) {
        {
            const bf16_t* ap = &A[(size_t)(m0 + ar) * U_ + k0 + ak];
            *(bf16x8*)&As[ar][ak]     = *(const bf16x8*)ap;
            *(bf16x8*)&As[ar][ak + 8] = *(const bf16x8*)(ap + 8);
        }
        {
            const bf16_t* bp = &Bw[(size_t)(k0 + bk) * VP_ + n0 + bn];
            bf16x8 v0 = *(const bf16x8*)bp;
            bf16x8 v1 = *(const bf16x8*)(bp + 8);
#pragma unroll
            for (int i = 0; i < 8; ++i) Bs[bn + i][bk] = v0[i];
#pragma unroll
            for (int i = 0; i < 8; ++i) Bs[bn + 8 + i][bk] = v1[i];
        }
        __syncthreads();

        bf16x8 af[4], bf[4];
#pragma unroll
        for (int m = 0; m < 4; ++m)
            af[m] = *(const bf16x8*)&As[wr * 64 + m * 16 + lr][lk * 8];
#pragma unroll
        for (int n = 0; n < 4; ++n)
            bf[n] = *(const bf16x8*)&Bs[wc * 64 + n * 16 + lr][lk * 8];
#pragma unroll
        for (int m = 0; m < 4; ++m)
#pragma unroll
            for (int n = 0; n < 4; ++n)
                acc[m][n] = __builtin_amdgcn_mfma_f32_16x16x32_bf16(
                    af[m], bf[n], acc[m][n], 0, 0, 0);
        __syncthreads();
    }

#pragma unroll
    for (int m = 0; m < 4; ++m) {
        const int row = m0 + wr * 64 + m * 16 + lk * 4;
#pragma unroll
        for (int n = 0; n < 4; ++n) {
            const int col = n0 + wc * 64 + n * 16 + lr;
            if (col < V_) {
                const float bb = bias[col];
#pragma unroll
                for (int r = 0; r < 4; ++r)
                    C[(size_t)(row + r) * V_ + col] = acc[m][n][r] + bb;
            }
        }
    }
}

// ---------------------------------------------------------------------------
extern "C" void kernel_launch(void* const* d_in, const int* in_sizes, int n_in,
                              void* d_out, int out_size, void* d_ws, size_t ws_size,
                              hipStream_t stream)
{
    const int*   tokens = (const int*)  d_in[0];
    const float* memory = (const float*)d_in[1];
    const float* h0     = (const float*)d_in[2];
    const float* c0     = (const float*)d_in[3];
    const float* emb    = (const float*)d_in[4];
    const float* Wx     = (const float*)d_in[5];
    const float* Uh     = (const float*)d_in[6];
    const float* bvec   = (const float*)d_in[7];
    const float* Wm     = (const float*)d_in[8];
    const float* Wa     = (const float*)d_in[9];
    const float* Wo     = (const float*)d_in[10];
    const float* bo     = (const float*)d_in[11];
    float* out = (float*)d_out;

    // ---- workspace layout (float units) ----
    float* ws = (float*)d_ws;
    size_t off = 0;
    float*   Wcomb  = ws + off; off += (size_t)2048 * U4_;      // 33.55 MB
    float*   keys   = ws + off; off += (size_t)B_ * S_ * U_;    // 13.11 MB
    float*   hc_all = ws + off; off += (size_t)B_ * T_ * 2048;  // 26.21 MB
    float*   zp     = ws + off; off += (size_t)8 * B_ * U4_;    //  8.39 MB
    float*   hcprev = ws + off; off += (size_t)B_ * 2048;       //  0.52 MB
    float*   x_emb  = ws + off; off += (size_t)B_ * T_ * E_;    //  1.28 MB
    unsigned* flags = (unsigned*)(ws + off); off += 256;        //  1 KB
    bf16_t*  wo_bf  = (bf16_t*)(ws + off); off += (size_t)1024 * VP_ / 2; // 61.6 MB
    const size_t need_bytes = off * sizeof(float);

    float* zemb = out;                             // d_out scratch (dead later)
    float*  attn_all = Wcomb;
    bf16_t* abf      = (bf16_t*)(Wcomb + (size_t)B_ * T_ * U_);

    const bool use_mfma = (ws_size >= need_bytes);

    (void)hipMemsetAsync(flags, 0, 256 * sizeof(unsigned), stream);

    // ---- pre-loop ----
    gather_emb<<<B_ * T_, 128, 0, stream>>>(tokens, emb, x_emb);
    gemm128<<<dim3(32, 25), 256, 0, stream>>>(
        x_emb, E_, Wx, U4_, zemb, U4_, U4_, E_, bvec);
    gemm128<<<dim3(32, 16), 256, 0, stream>>>(
        Wa, U_, Wx + (size_t)E_ * U4_, U4_, Wcomb, U4_, U4_, U_, nullptr);
    add_inplace<<<(1024 * U4_) / 256, 256, 0, stream>>>(Wcomb, Uh, 1024 * U4_);
    gemm128<<<dim3(8, 25), 256, 0, stream>>>(
        memory, U_, Wm, U_, keys, U_, U_, U_, nullptr);
    zgemm_partial<<<dim3(64, 4), 256, 0, stream>>>(h0, U_, Uh, zp);
    if (use_mfma)
        cast_wo_bf16<<<dim3((VP_ + 255) / 256, 1024), 256, 0, stream>>>(Wo, wo_bf);

    // ---- persistent recurrent loop ----
    decoder_loop7<<<256, 512, 0, stream>>>(
        zemb, Wcomb, keys, memory, c0, hcprev, zp, hc_all, flags);

    // ---- post-loop ----
    gemm128<<<dim3(8, 25), 256, 0, stream>>>(
        hc_all, 2048, Wa, U_, attn_all, U_, U_, 2048, nullptr);

    if (use_mfma) {
        cast_bf16<<<2048, 256, 0, stream>>>(attn_all, abf, B_ * T_ * U_);
        gemm_wo_mfma<<<dim3(VP_ / 128, 25), 256, 0, stream>>>(abf, wo_bf, bo, out);
    } else {
        gemm128<<<dim3(235, 25), 256, 0, stream>>>(
            attn_all, U_, Wo, V_, out, V_, V_, U_, bo);
    }
}

// Round 13
// 4785.538 us; speedup vs baseline: 1.4447x; 1.0753x over previous
//
#include <hip/hip_runtime.h>
#include <math.h>

#define B_  64
#define T_  50
#define S_  50
#define U_  1024
#define E_  100
#define V_  30001
#define U4_ 4096
#define VP_ 30080   // V padded to a multiple of 128 for bf16 staging alignment

typedef __bf16 bf16_t;
typedef bf16_t bf16x8 __attribute__((ext_vector_type(8)));
typedef float  f32x4  __attribute__((ext_vector_type(4)));
typedef unsigned long long u64_t;

// ---------------------------------------------------------------------------
// Coherence-point accessors (SYSTEM scope -> sc0+sc1, bypass L1/L2; proven
// correct r11/r12). All data accesses 8B/16B wide, lane-contiguous.
// ---------------------------------------------------------------------------
__device__ __forceinline__ float2 scload8(const float* p) {
    u64_t v = __hip_atomic_load((const u64_t*)p, __ATOMIC_RELAXED,
                                __HIP_MEMORY_SCOPE_SYSTEM);
    union { u64_t u; float2 f; } c; c.u = v; return c.f;
}
__device__ __forceinline__ void scstore8(float* p, float x, float y) {
    union { u64_t u; float2 f; } c; c.f = make_float2(x, y);
    __hip_atomic_store((u64_t*)p, c.u, __ATOMIC_RELAXED,
                       __HIP_MEMORY_SCOPE_SYSTEM);
}
__device__ __forceinline__ unsigned scload_u(const unsigned* p) {
    return __hip_atomic_load(p, __ATOMIC_RELAXED, __HIP_MEMORY_SCOPE_SYSTEM);
}
__device__ __forceinline__ void scadd_u(unsigned* p) {
    __hip_atomic_fetch_add(p, 1u, __ATOMIC_RELAXED, __HIP_MEMORY_SCOPE_SYSTEM);
}
__device__ __forceinline__ void scstore4(float* p, f32x4 v) {
    asm volatile("global_store_dwordx4 %0, %1, off sc0 sc1"
                 :: "v"(p), "v"(v) : "memory");
}
__device__ __forceinline__ void vm_drain() {
    asm volatile("s_waitcnt vmcnt(0)" ::: "memory");
}
__device__ __forceinline__ void cbar() { asm volatile("" ::: "memory"); }

// ---------------------------------------------------------------------------
// Generic tiled f32 GEMM: C[M,N] = A[M,K] @ B[K,N] (+ bias).
// ---------------------------------------------------------------------------
__global__ __launch_bounds__(256) void gemm128(
    const float* __restrict__ A, int lda,
    const float* __restrict__ Bm, int ldb,
    float* __restrict__ C, int ldc,
    int N, int K, const float* __restrict__ bias)
{
    __shared__ float As[8][132];
    __shared__ float Bs[8][132];

    const int n0  = blockIdx.x * 128;
    const int m0  = blockIdx.y * 128;
    const int tid = threadIdx.x;
    const int tx  = tid & 15, ty = tid >> 4;

    float acc[8][8];
#pragma unroll
    for (int i = 0; i < 8; ++i)
#pragma unroll
        for (int j = 0; j < 8; ++j) acc[i][j] = 0.f;

    const int ra = tid >> 1, ca = (tid & 1) * 4;
    const int rb = tid >> 5, cb = (tid & 31) * 4;
    const bool fast_b = ((ldb & 3) == 0) && (n0 + 128 <= N);

    for (int k0 = 0; k0 < K; k0 += 8) {
        const float* ap = &A[(size_t)(m0 + ra) * lda + k0 + ca];
        float4 av;
        if (k0 + 8 <= K) {
            av = *(const float4*)ap;
        } else {
            av.x = (k0 + ca + 0 < K) ? ap[0] : 0.f;
            av.y = (k0 + ca + 1 < K) ? ap[1] : 0.f;
            av.z = (k0 + ca + 2 < K) ? ap[2] : 0.f;
            av.w = (k0 + ca + 3 < K) ? ap[3] : 0.f;
        }
        As[ca + 0][ra] = av.x;
        As[ca + 1][ra] = av.y;
        As[ca + 2][ra] = av.z;
        As[ca + 3][ra] = av.w;

        float4 bv = make_float4(0.f, 0.f, 0.f, 0.f);
        if (k0 + rb < K) {
            const float* bp = &Bm[(size_t)(k0 + rb) * ldb];
            if (fast_b) {
                bv = *(const float4*)&bp[n0 + cb];
            } else {
                bv.x = (n0 + cb + 0 < N) ? bp[n0 + cb + 0] : 0.f;
                bv.y = (n0 + cb + 1 < N) ? bp[n0 + cb + 1] : 0.f;
                bv.z = (n0 + cb + 2 < N) ? bp[n0 + cb + 2] : 0.f;
                bv.w = (n0 + cb + 3 < N) ? bp[n0 + cb + 3] : 0.f;
            }
        }
        *(float4*)&Bs[rb][cb] = bv;
        __syncthreads();

#pragma unroll
        for (int kk = 0; kk < 8; ++kk) {
            float4 a0 = *(const float4*)&As[kk][ty * 4];
            float4 a1 = *(const float4*)&As[kk][64 + ty * 4];
            float4 b0 = *(const float4*)&Bs[kk][tx * 4];
            float4 b1 = *(const float4*)&Bs[kk][64 + tx * 4];
            float a_[8] = {a0.x, a0.y, a0.z, a0.w, a1.x, a1.y, a1.z, a1.w};
            float b_[8] = {b0.x, b0.y, b0.z, b0.w, b1.x, b1.y, b1.z, b1.w};
#pragma unroll
            for (int i = 0; i < 8; ++i)
#pragma unroll
                for (int j = 0; j < 8; ++j)
                    acc[i][j] = fmaf(a_[i], b_[j], acc[i][j]);
        }
        __syncthreads();
    }

#pragma unroll
    for (int i = 0; i < 8; ++i) {
        int row = m0 + ((i < 4) ? (ty * 4 + i) : (64 + ty * 4 + (i - 4)));
#pragma unroll
        for (int j = 0; j < 8; ++j) {
            int col = n0 + ((j < 4) ? (tx * 4 + j) : (64 + tx * 4 + (j - 4)));
            if (col < N) {
                float v = acc[i][j];
                if (bias) v += bias[col];
                C[(size_t)row * ldc + col] = v;
            }
        }
    }
}

__global__ void add_inplace(float* __restrict__ dst, const float* __restrict__ src, int n)
{
    int i = blockIdx.x * blockDim.x + threadIdx.x;
    if (i < n) dst[i] += src[i];
}

__global__ void gather_emb(const int* __restrict__ tokens,
                           const float* __restrict__ emb,
                           float* __restrict__ xe)
{
    const int r = blockIdx.x;
    const int e = threadIdx.x;
    if (e < E_) xe[(size_t)r * E_ + e] = emb[(size_t)tokens[r] * E_ + e];
}

__global__ void cast_bf16(const float* __restrict__ src, bf16_t* __restrict__ dst, int n)
{
    int i = blockIdx.x * blockDim.x + threadIdx.x;
    const int stride = gridDim.x * blockDim.x;
    for (; i < n; i += stride) dst[i] = (bf16_t)src[i];
}

__global__ void cast_wo_bf16(const float* __restrict__ wo, bf16_t* __restrict__ dst)
{
    const int col = blockIdx.x * 256 + threadIdx.x;
    const int k   = blockIdx.y;
    if (col < VP_)
        dst[(size_t)k * VP_ + col] =
            (col < V_) ? (bf16_t)wo[(size_t)k * V_ + col] : (bf16_t)0.f;
}

// ---------------------------------------------------------------------------
// Split-K GEMM for t=0: zp[(ks*64+b)*4096+n] = sum_{k in slice} h0[b][k]*Uh[k][n]
// ---------------------------------------------------------------------------
__global__ __launch_bounds__(256) void zgemm_partial(
    const float* __restrict__ A, int lda,
    const float* __restrict__ Bm,
    float* __restrict__ zp)
{
    __shared__ float As[64][17];
    __shared__ float Bs[16][68];

    const int n0     = blockIdx.x * 64;
    const int ks     = blockIdx.y;
    const int k_base = ks * 256;
    const int tid    = threadIdx.x;
    const int tx     = tid & 15, ty = tid >> 4;

    float acc[4][4];
#pragma unroll
    for (int i = 0; i < 4; ++i)
#pragma unroll
        for (int j = 0; j < 4; ++j) acc[i][j] = 0.f;

    const int ra = tid >> 2, ca = (tid & 3) * 4;
    const int rb = tid >> 4, cb = (tid & 15) * 4;

    for (int kt = 0; kt < 16; ++kt) {
        const int k0 = k_base + kt * 16;
        float4 av = *(const float4*)&A[(size_t)ra * lda + k0 + ca];
        As[ra][ca + 0] = av.x;
        As[ra][ca + 1] = av.y;
        As[ra][ca + 2] = av.z;
        As[ra][ca + 3] = av.w;
        float4 bv = *(const float4*)&Bm[(size_t)(k0 + rb) * U4_ + n0 + cb];
        *(float4*)&Bs[rb][cb] = bv;
        __syncthreads();
#pragma unroll
        for (int kk = 0; kk < 16; ++kk) {
            float a_[4];
#pragma unroll
            for (int i = 0; i < 4; ++i) a_[i] = As[ty * 4 + i][kk];
            float4 bq = *(const float4*)&Bs[kk][tx * 4];
            float b_[4] = {bq.x, bq.y, bq.z, bq.w};
#pragma unroll
            for (int i = 0; i < 4; ++i)
#pragma unroll
                for (int j = 0; j < 4; ++j)
                    acc[i][j] = fmaf(a_[i], b_[j], acc[i][j]);
        }
        __syncthreads();
    }

#pragma unroll
    for (int i = 0; i < 4; ++i)
        *(float4*)&zp[((size_t)ks * 64 + ty * 4 + i) * U4_ + n0 + tx * 4] =
            make_float4(acc[i][0], acc[i][1], acc[i][2], acc[i][3]);
}

// ---------------------------------------------------------------------------
// Persistent decoder loop v8 — r12 pipeline with TREE'D FLAGS.
// r12's single-line flag counters serialized 256 (zp) / 64 (h,ctx) RMWs on
// one L3 line per step, directly on the critical path (~58 us/step). Split:
//   zp-done : 16 group flags (flags[g*32],      g=0..15), 16 adds each
//   h-done  :  8 group flags (flags[512+g*32],  g=0..7),   8 adds each
//   ctx-done:  8 group flags (flags[768+g*32],  g=0..7),   8 adds each
// Consumers poll all group flags, one lane per flag.
// ---------------------------------------------------------------------------
__global__ __launch_bounds__(512) void decoder_loop8(
    const float* __restrict__ zemb,   // [3200][4096] (in d_out)
    const float* __restrict__ Wcomb,  // [2048][4096]
    const float* __restrict__ keys,   // [64][50][1024]
    const float* __restrict__ memory, // [64][50][1024]
    const float* __restrict__ c0,
    float* __restrict__ hcprev,       // [64][2048]   (sc-ops only)
    float* __restrict__ zp,           // [8][64][4096] (sc-ops only)
    float* __restrict__ hc_all,       // [64][50][2048] (plain)
    unsigned* flags)
{
    __shared__ float Bw[256 * 128];   // 128 KB persistent Wcomb slice
    __shared__ float As[2][32][68];
    __shared__ float hs[1024];
    __shared__ float sc[64];
    __shared__ float al[64];

    const int beta = blockIdx.x;
    const int tid  = threadIdx.x;

    const int nt = beta & 31, ks = beta >> 5;
    const int koff = ks * 256;
    const int c0c  = nt * 128;

    // ---- load persistent Wcomb slice into LDS (once) ----
    {
        const int k_sub = tid >> 5;
        const int c4    = (tid & 31) * 4;
#pragma unroll
        for (int it = 0; it < 16; ++it) {
            int k = it * 16 + k_sub;
            *(float4*)&Bw[k * 128 + c4] =
                *(const float4*)&Wcomb[(size_t)(koff + k) * U4_ + c0c + c4];
        }
    }

    const int b  = beta;
    const int u2 = tid * 2;           // BC thread owns u = {u2, u2+1}
    float creg[2] = {0.f, 0.f};
    if (beta < 64) {
        float2 cv = *(const float2*)&c0[b * U_ + u2];
        creg[0] = cv.x;
        creg[1] = cv.y;
    }
    __syncthreads();

    // phase-A indices
    const int tx   = tid & 31;
    const int ty   = tid >> 5;
    const int srow = tid >> 3;
    const int sk4  = (tid & 7) * 4;

    for (int t = 0; t < T_; ++t) {
        const int KS = t ? 8 : 4;

        // ---------------- phase A (t>=1): zp = hcprev-slice @ Bw ------------
        if (t) {
            // wait: ks<4 needs h(t-1) [8 groups x 8 adds/step];
            //       ks>=4 needs ctx(t-1) [same]
            {
                const unsigned tgt = 8u * (unsigned)t;
                const unsigned* fb = (ks < 4) ? &flags[512] : &flags[768];
                if (tid < 8) {
                    const unsigned* f = fb + tid * 32;
                    while (scload_u(f) < tgt) __builtin_amdgcn_s_sleep(1);
                }
                __syncthreads();
                cbar();
            }

            float acc[4][4];
#pragma unroll
            for (int i = 0; i < 4; ++i)
#pragma unroll
                for (int j = 0; j < 4; ++j) acc[i][j] = 0.f;

            const float* ap = &hcprev[srow * 2048 + koff];
            float2 pf0, pf1;
            {
                float2 s0 = scload8(&ap[sk4]);
                float2 s1 = scload8(&ap[sk4 + 2]);
                As[0][sk4 + 0][srow] = s0.x;
                As[0][sk4 + 1][srow] = s0.y;
                As[0][sk4 + 2][srow] = s1.x;
                As[0][sk4 + 3][srow] = s1.y;
                pf0 = scload8(&ap[32 + sk4]);
                pf1 = scload8(&ap[32 + sk4 + 2]);
            }
            __syncthreads();

            for (int kc = 0; kc < 8; ++kc) {
                const int cur = kc & 1;
                const float* bwp = &Bw[(kc * 32) * 128];
#pragma unroll
                for (int kk = 0; kk < 32; ++kk) {
                    float4 af = *(const float4*)&As[cur][kk][ty * 4];
                    float4 bf = *(const float4*)&bwp[kk * 128 + tx * 4];
                    float a_[4] = {af.x, af.y, af.z, af.w};
                    float b_[4] = {bf.x, bf.y, bf.z, bf.w};
#pragma unroll
                    for (int i = 0; i < 4; ++i)
#pragma unroll
                        for (int j = 0; j < 4; ++j)
                            acc[i][j] = fmaf(a_[i], b_[j], acc[i][j]);
                }
                if (kc < 7) {
                    As[cur ^ 1][sk4 + 0][srow] = pf0.x;
                    As[cur ^ 1][sk4 + 1][srow] = pf0.y;
                    As[cur ^ 1][sk4 + 2][srow] = pf1.x;
                    As[cur ^ 1][sk4 + 3][srow] = pf1.y;
                    if (kc < 6) {
                        pf0 = scload8(&ap[(kc + 2) * 32 + sk4]);
                        pf1 = scload8(&ap[(kc + 2) * 32 + sk4 + 2]);
                    }
                }
                __syncthreads();
            }
#pragma unroll
            for (int i = 0; i < 4; ++i) {
                int m = ty * 4 + i;
                f32x4 vv = {acc[i][0], acc[i][1], acc[i][2], acc[i][3]};
                scstore4(&zp[((size_t)ks * 64 + m) * U4_ + c0c + tx * 4], vv);
            }
            vm_drain();
            __syncthreads();
            if (tid == 0) scadd_u(&flags[(beta & 15) * 32]);  // zp group flag
        }

        // ---------------- phase BC: gates + attention (blocks < 64) ---------
        if (beta < 64) {
            if (t) {
                // wait: all 16 zp groups to reach 16*t
                const unsigned tgt = 16u * (unsigned)t;
                if (tid < 16) {
                    const unsigned* f = &flags[tid * 32];
                    while (scload_u(f) < tgt) __builtin_amdgcn_s_sleep(1);
                }
                __syncthreads();
                cbar();
            }

            const float* ze = &zemb[((size_t)b * T_ + t) * U4_];
            float zgx[4], zgy[4];
#pragma unroll
            for (int g = 0; g < 4; ++g) {
                float2 a = *(const float2*)&ze[g * U_ + u2];  // plain cached
                zgx[g] = a.x;
                zgy[g] = a.y;
            }
#pragma unroll
            for (int s = 0; s < 8; ++s)
                if (s < KS) {
#pragma unroll
                    for (int g = 0; g < 4; ++g) {
                        float2 v = scload8(&zp[((size_t)s * 64 + b) * U4_ + g * U_ + u2]);
                        zgx[g] += v.x;
                        zgy[g] += v.y;
                    }
                }

            const float six = 1.f / (1.f + expf(-zgx[0]));
            const float sfx = 1.f / (1.f + expf(-zgx[1]));
            const float tgx = tanhf(zgx[2]);
            const float sox = 1.f / (1.f + expf(-zgx[3]));
            const float cnx = sfx * creg[0] + six * tgx;
            creg[0] = cnx;
            const float hnx = sox * tanhf(cnx);

            const float siy = 1.f / (1.f + expf(-zgy[0]));
            const float sfy = 1.f / (1.f + expf(-zgy[1]));
            const float tgy = tanhf(zgy[2]);
            const float soy = 1.f / (1.f + expf(-zgy[3]));
            const float cny = sfy * creg[1] + siy * tgy;
            creg[1] = cny;
            const float hny = soy * tanhf(cny);

            hs[u2]     = hnx;
            hs[u2 + 1] = hny;
            scstore8(&hcprev[b * 2048 + u2], hnx, hny);
            *(float2*)&hc_all[((size_t)b * T_ + t) * 2048 + u2] =
                make_float2(hnx, hny);
            vm_drain();
            __syncthreads();
            if (tid == 0) scadd_u(&flags[512 + (b & 7) * 32]);  // h group flag

            // scores (keys plain cached, L2-resident — no fences ever)
            const int lane = tid & 63, w = tid >> 6;
            for (int s = w; s < S_; s += 8) {
                const float* kp = &keys[((size_t)b * S_ + s) * U_ + lane * 16];
                const float* hp = &hs[lane * 16];
                float p = 0.f;
#pragma unroll
                for (int q = 0; q < 4; ++q) {
                    float4 kv = *(const float4*)&kp[q * 4];
                    float4 hv = *(const float4*)&hp[q * 4];
                    p = fmaf(hv.x, kv.x, p);
                    p = fmaf(hv.y, kv.y, p);
                    p = fmaf(hv.z, kv.z, p);
                    p = fmaf(hv.w, kv.w, p);
                }
#pragma unroll
                for (int off = 32; off > 0; off >>= 1)
                    p += __shfl_xor(p, off);
                if (lane == 0) sc[s] = p;
            }
            __syncthreads();

            if (tid < 64) {
                float v = (tid < S_) ? sc[tid] : -INFINITY;
                float m = v;
#pragma unroll
                for (int off = 32; off > 0; off >>= 1)
                    m = fmaxf(m, __shfl_xor(m, off));
                float e = (tid < S_) ? expf(v - m) : 0.f;
                float ssum = e;
#pragma unroll
                for (int off = 32; off > 0; off >>= 1)
                    ssum += __shfl_xor(ssum, off);
                if (tid < S_) al[tid] = e / ssum;
            }
            __syncthreads();

            // ctx (memory plain cached, L2-resident)
            {
                const float2* mp = (const float2*)&memory[(size_t)b * S_ * U_];
                float cx = 0.f, cy = 0.f;
#pragma unroll 10
                for (int s = 0; s < S_; ++s) {
                    float2 mv = mp[s * 512 + tid];
                    const float a = al[s];
                    cx = fmaf(a, mv.x, cx);
                    cy = fmaf(a, mv.y, cy);
                }
                scstore8(&hcprev[b * 2048 + U_ + u2], cx, cy);
                *(float2*)&hc_all[((size_t)b * T_ + t) * 2048 + U_ + u2] =
                    make_float2(cx, cy);
            }
            vm_drain();
            __syncthreads();
            if (tid == 0) scadd_u(&flags[768 + (b & 7) * 32]);  // ctx group flag
        }
    }
}

// ---------------------------------------------------------------------------
// bf16 MFMA GEMM: C[3200][V] = A[3200][1024] @ B[1024][VP_] + bias.
// ---------------------------------------------------------------------------
__global__ __launch_bounds__(256) void gemm_wo_mfma(
    const bf16_t* __restrict__ A,
    const bf16_t* __restrict__ Bw,
    const float*  __restrict__ bias,
    float* __restrict__ C)
{
    __shared__ bf16_t As[128][40];
    __shared__ bf16_t Bs[128][40];

    const int n0  = blockIdx.x * 128;
    const int m0  = blockIdx.y * 128;
    const int tid = threadIdx.x;
    const int wave = tid >> 6, lane = tid & 63;
    const int wr = wave >> 1, wc = wave & 1;
    const int lr = lane & 15;
    const int lk = lane >> 4;

    f32x4 acc[4][4] = {};

    const int ar = tid >> 1;
    const int ak = (tid & 1) * 16;
    const int bk = tid >> 3;
    const int bn = (tid & 7) * 16;

    for (int k0 = 0; k0 < U_; k0 += 32) {
        {
            const bf16_t* ap = &A[(size_t)(m0 + ar) * U_ + k0 + ak];
            *(bf16x8*)&As[ar][ak]     = *(const bf16x8*)ap;
            *(bf16x8*)&As[ar][ak + 8] = *(const bf16x8*)(ap + 8);
        }
        {
            const bf16_t* bp = &Bw[(size_t)(k0 + bk) * VP_ + n0 + bn];
            bf16x8 v0 = *(const bf16x8*)bp;
            bf16x8 v1 = *(const bf16x8*)(bp + 8);
#pragma unroll
            for (int i = 0; i < 8; ++i) Bs[bn + i][bk] = v0[i];
#pragma unroll
            for (int i = 0; i < 8; ++i) Bs[bn + 8 + i][bk] = v1[i];
        }
        __syncthreads();

        bf16x8 af[4], bf[4];
#pragma unroll
        for (int m = 0; m < 4; ++m)
            af[m] = *(const bf16x8*)&As[wr * 64 + m * 16 + lr][lk * 8];
#pragma unroll
        for (int n = 0; n < 4; ++n)
            bf[n] = *(const bf16x8*)&Bs[wc * 64 + n * 16 + lr][lk * 8];
#pragma unroll
        for (int m = 0; m < 4; ++m)
#pragma unroll
            for (int n = 0; n < 4; ++n)
                acc[m][n] = __builtin_amdgcn_mfma_f32_16x16x32_bf16(
                    af[m], bf[n], acc[m][n], 0, 0, 0);
        __syncthreads();
    }

#pragma unroll
    for (int m = 0; m < 4; ++m) {
        const int row = m0 + wr * 64 + m * 16 + lk * 4;
#pragma unroll
        for (int n = 0; n < 4; ++n) {
            const int col = n0 + wc * 64 + n * 16 + lr;
            if (col < V_) {
                const float bb = bias[col];
#pragma unroll
                for (int r = 0; r < 4; ++r)
                    C[(size_t)(row + r) * V_ + col] = acc[m][n][r] + bb;
            }
        }
    }
}

// ---------------------------------------------------------------------------
extern "C" void kernel_launch(void* const* d_in, const int* in_sizes, int n_in,
                              void* d_out, int out_size, void* d_ws, size_t ws_size,
                              hipStream_t stream)
{
    const int*   tokens = (const int*)  d_in[0];
    const float* memory = (const float*)d_in[1];
    const float* h0     = (const float*)d_in[2];
    const float* c0     = (const float*)d_in[3];
    const float* emb    = (const float*)d_in[4];
    const float* Wx     = (const float*)d_in[5];
    const float* Uh     = (const float*)d_in[6];
    const float* bvec   = (const float*)d_in[7];
    const float* Wm     = (const float*)d_in[8];
    const float* Wa     = (const float*)d_in[9];
    const float* Wo     = (const float*)d_in[10];
    const float* bo     = (const float*)d_in[11];
    float* out = (float*)d_out;

    // ---- workspace layout (float units) ----
    float* ws = (float*)d_ws;
    size_t off = 0;
    float*   Wcomb  = ws + off; off += (size_t)2048 * U4_;      // 33.55 MB
    float*   keys   = ws + off; off += (size_t)B_ * S_ * U_;    // 13.11 MB
    float*   hc_all = ws + off; off += (size_t)B_ * T_ * 2048;  // 26.21 MB
    float*   zp     = ws + off; off += (size_t)8 * B_ * U4_;    //  8.39 MB
    float*   hcprev = ws + off; off += (size_t)B_ * 2048;       //  0.52 MB
    float*   x_emb  = ws + off; off += (size_t)B_ * T_ * E_;    //  1.28 MB
    unsigned* flags = (unsigned*)(ws + off); off += 1024;       //  4 KB
    bf16_t*  wo_bf  = (bf16_t*)(ws + off); off += (size_t)1024 * VP_ / 2; // 61.6 MB
    const size_t need_bytes = off * sizeof(float);

    float* zemb = out;                             // d_out scratch (dead later)
    float*  attn_all = Wcomb;
    bf16_t* abf      = (bf16_t*)(Wcomb + (size_t)B_ * T_ * U_);

    const bool use_mfma = (ws_size >= need_bytes);

    (void)hipMemsetAsync(flags, 0, 1024 * sizeof(unsigned), stream);

    // ---- pre-loop ----
    gather_emb<<<B_ * T_, 128, 0, stream>>>(tokens, emb, x_emb);
    gemm128<<<dim3(32, 25), 256, 0, stream>>>(
        x_emb, E_, Wx, U4_, zemb, U4_, U4_, E_, bvec);
    gemm128<<<dim3(32, 16), 256, 0, stream>>>(
        Wa, U_, Wx + (size_t)E_ * U4_, U4_, Wcomb, U4_, U4_, U_, nullptr);
    add_inplace<<<(1024 * U4_) / 256, 256, 0, stream>>>(Wcomb, Uh, 1024 * U4_);
    gemm128<<<dim3(8, 25), 256, 0, stream>>>(
        memory, U_, Wm, U_, keys, U_, U_, U_, nullptr);
    zgemm_partial<<<dim3(64, 4), 256, 0, stream>>>(h0, U_, Uh, zp);
    if (use_mfma)
        cast_wo_bf16<<<dim3((VP_ + 255) / 256, 1024), 256, 0, stream>>>(Wo, wo_bf);

    // ---- persistent recurrent loop ----
    decoder_loop8<<<256, 512, 0, stream>>>(
        zemb, Wcomb, keys, memory, c0, hcprev, zp, hc_all, flags);

    // ---- post-loop ----
    gemm128<<<dim3(8, 25), 256, 0, stream>>>(
        hc_all, 2048, Wa, U_, attn_all, U_, U_, 2048, nullptr);

    if (use_mfma) {
        cast_bf16<<<2048, 256, 0, stream>>>(attn_all, abf, B_ * T_ * U_);
        gemm_wo_mfma<<<dim3(VP_ / 128, 25), 256, 0, stream>>>(abf, wo_bf, bo, out);
    } else {
        gemm128<<<dim3(235, 25), 256, 0, stream>>>(
            attn_all, U_, Wo, V_, out, V_, V_, U_, bo);
    }
}

// Round 14
// 3473.026 us; speedup vs baseline: 1.9907x; 1.3779x over previous
//
#include <hip/hip_runtime.h>
#include <math.h>

#define B_  64
#define T_  50
#define S_  50
#define U_  1024
#define E_  100
#define V_  30001
#define U4_ 4096
#define VP_ 30080       // V padded to a multiple of 128 for bf16 staging
#define HCSTR_ 131136   // hcbuf plane stride: 64*2048 + 64 pad floats

typedef __bf16 bf16_t;
typedef bf16_t bf16x8 __attribute__((ext_vector_type(8)));
typedef float  f32x4  __attribute__((ext_vector_type(4)));
typedef unsigned long long u64_t;

// ---------------------------------------------------------------------------
// Coherence-point accessors (SYSTEM scope -> sc0+sc1, bypass L1/L2; proven
// r11-r13). Producers sc-write; consumers either sc-read (zp: per-block
// private rows) or PLAIN-cached-read fresh-per-step addresses (hcbuf:
// shared rows — L2-shareable because each plane is written exactly once
// per dispatch and the dispatch-start acquire invalidated stale lines).
// ---------------------------------------------------------------------------
__device__ __forceinline__ float2 scload8(const float* p) {
    u64_t v = __hip_atomic_load((const u64_t*)p, __ATOMIC_RELAXED,
                                __HIP_MEMORY_SCOPE_SYSTEM);
    union { u64_t u; float2 f; } c; c.u = v; return c.f;
}
__device__ __forceinline__ void scstore8(float* p, float x, float y) {
    union { u64_t u; float2 f; } c; c.f = make_float2(x, y);
    __hip_atomic_store((u64_t*)p, c.u, __ATOMIC_RELAXED,
                       __HIP_MEMORY_SCOPE_SYSTEM);
}
__device__ __forceinline__ unsigned scload_u(const unsigned* p) {
    return __hip_atomic_load(p, __ATOMIC_RELAXED, __HIP_MEMORY_SCOPE_SYSTEM);
}
__device__ __forceinline__ void scadd_u(unsigned* p) {
    __hip_atomic_fetch_add(p, 1u, __ATOMIC_RELAXED, __HIP_MEMORY_SCOPE_SYSTEM);
}
__device__ __forceinline__ void vm_drain() {
    asm volatile("s_waitcnt vmcnt(0)" ::: "memory");
}
__device__ __forceinline__ void cbar() { asm volatile("" ::: "memory"); }

// ---------------------------------------------------------------------------
// Generic tiled f32 GEMM: C[M,N] = A[M,K] @ B[K,N] (+ bias).
// ---------------------------------------------------------------------------
__global__ __launch_bounds__(256) void gemm128(
    const float* __restrict__ A, int lda,
    const float* __restrict__ Bm, int ldb,
    float* __restrict__ C, int ldc,
    int N, int K, const float* __restrict__ bias)
{
    __shared__ float As[8][132];
    __shared__ float Bs[8][132];

    const int n0  = blockIdx.x * 128;
    const int m0  = blockIdx.y * 128;
    const int tid = threadIdx.x;
    const int tx  = tid & 15, ty = tid >> 4;

    float acc[8][8];
#pragma unroll
    for (int i = 0; i < 8; ++i)
#pragma unroll
        for (int j = 0; j < 8; ++j) acc[i][j] = 0.f;

    const int ra = tid >> 1, ca = (tid & 1) * 4;
    const int rb = tid >> 5, cb = (tid & 31) * 4;
    const bool fast_b = ((ldb & 3) == 0) && (n0 + 128 <= N);

    for (int k0 = 0; k0 < K; k0 += 8) {
        const float* ap = &A[(size_t)(m0 + ra) * lda + k0 + ca];
        float4 av;
        if (k0 + 8 <= K) {
            av = *(const float4*)ap;
        } else {
            av.x = (k0 + ca + 0 < K) ? ap[0] : 0.f;
            av.y = (k0 + ca + 1 < K) ? ap[1] : 0.f;
            av.z = (k0 + ca + 2 < K) ? ap[2] : 0.f;
            av.w = (k0 + ca + 3 < K) ? ap[3] : 0.f;
        }
        As[ca + 0][ra] = av.x;
        As[ca + 1][ra] = av.y;
        As[ca + 2][ra] = av.z;
        As[ca + 3][ra] = av.w;

        float4 bv = make_float4(0.f, 0.f, 0.f, 0.f);
        if (k0 + rb < K) {
            const float* bp = &Bm[(size_t)(k0 + rb) * ldb];
            if (fast_b) {
                bv = *(const float4*)&bp[n0 + cb];
            } else {
                bv.x = (n0 + cb + 0 < N) ? bp[n0 + cb + 0] : 0.f;
                bv.y = (n0 + cb + 1 < N) ? bp[n0 + cb + 1] : 0.f;
                bv.z = (n0 + cb + 2 < N) ? bp[n0 + cb + 2] : 0.f;
                bv.w = (n0 + cb + 3 < N) ? bp[n0 + cb + 3] : 0.f;
            }
        }
        *(float4*)&Bs[rb][cb] = bv;
        __syncthreads();

#pragma unroll
        for (int kk = 0; kk < 8; ++kk) {
            float4 a0 = *(const float4*)&As[kk][ty * 4];
            float4 a1 = *(const float4*)&As[kk][64 + ty * 4];
            float4 b0 = *(const float4*)&Bs[kk][tx * 4];
            float4 b1 = *(const float4*)&Bs[kk][64 + tx * 4];
            float a_[8] = {a0.x, a0.y, a0.z, a0.w, a1.x, a1.y, a1.z, a1.w};
            float b_[8] = {b0.x, b0.y, b0.z, b0.w, b1.x, b1.y, b1.z, b1.w};
#pragma unroll
            for (int i = 0; i < 8; ++i)
#pragma unroll
                for (int j = 0; j < 8; ++j)
                    acc[i][j] = fmaf(a_[i], b_[j], acc[i][j]);
        }
        __syncthreads();
    }

#pragma unroll
    for (int i = 0; i < 8; ++i) {
        int row = m0 + ((i < 4) ? (ty * 4 + i) : (64 + ty * 4 + (i - 4)));
#pragma unroll
        for (int j = 0; j < 8; ++j) {
            int col = n0 + ((j < 4) ? (tx * 4 + j) : (64 + tx * 4 + (j - 4)));
            if (col < N) {
                float v = acc[i][j];
                if (bias) v += bias[col];
                C[(size_t)row * ldc + col] = v;
            }
        }
    }
}

__global__ void add_inplace(float* __restrict__ dst, const float* __restrict__ src, int n)
{
    int i = blockIdx.x * blockDim.x + threadIdx.x;
    if (i < n) dst[i] += src[i];
}

__global__ void gather_emb(const int* __restrict__ tokens,
                           const float* __restrict__ emb,
                           float* __restrict__ xe)
{
    const int r = blockIdx.x;
    const int e = threadIdx.x;
    if (e < E_) xe[(size_t)r * E_ + e] = emb[(size_t)tokens[r] * E_ + e];
}

__global__ void cast_bf16(const float* __restrict__ src, bf16_t* __restrict__ dst, int n)
{
    int i = blockIdx.x * blockDim.x + threadIdx.x;
    const int stride = gridDim.x * blockDim.x;
    for (; i < n; i += stride) dst[i] = (bf16_t)src[i];
}

__global__ void cast_wo_bf16(const float* __restrict__ wo, bf16_t* __restrict__ dst)
{
    const int col = blockIdx.x * 256 + threadIdx.x;
    const int k   = blockIdx.y;
    if (col < VP_)
        dst[(size_t)k * VP_ + col] =
            (col < V_) ? (bf16_t)wo[(size_t)k * V_ + col] : (bf16_t)0.f;
}

// ---------------------------------------------------------------------------
// Split-K GEMM for t=0: zp[(ks*64+b)*4096+n] = sum_{k in 256-slice} h0@Uh.
// 4 slices cover K=1024. Plain stores (kernel-end flush makes them visible
// to the loop's sc-reads).
// ---------------------------------------------------------------------------
__global__ __launch_bounds__(256) void zgemm_partial(
    const float* __restrict__ A, int lda,
    const float* __restrict__ Bm,
    float* __restrict__ zp)
{
    __shared__ float As[64][17];
    __shared__ float Bs[16][68];

    const int n0     = blockIdx.x * 64;
    const int ks     = blockIdx.y;
    const int k_base = ks * 256;
    const int tid    = threadIdx.x;
    const int tx     = tid & 15, ty = tid >> 4;

    float acc[4][4];
#pragma unroll
    for (int i = 0; i < 4; ++i)
#pragma unroll
        for (int j = 0; j < 4; ++j) acc[i][j] = 0.f;

    const int ra = tid >> 2, ca = (tid & 3) * 4;
    const int rb = tid >> 4, cb = (tid & 15) * 4;

    for (int kt = 0; kt < 16; ++kt) {
        const int k0 = k_base + kt * 16;
        float4 av = *(const float4*)&A[(size_t)ra * lda + k0 + ca];
        As[ra][ca + 0] = av.x;
        As[ra][ca + 1] = av.y;
        As[ra][ca + 2] = av.z;
        As[ra][ca + 3] = av.w;
        float4 bv = *(const float4*)&Bm[(size_t)(k0 + rb) * U4_ + n0 + cb];
        *(float4*)&Bs[rb][cb] = bv;
        __syncthreads();
#pragma unroll
        for (int kk = 0; kk < 16; ++kk) {
            float a_[4];
#pragma unroll
            for (int i = 0; i < 4; ++i) a_[i] = As[ty * 4 + i][kk];
            float4 bq = *(const float4*)&Bs[kk][tx * 4];
            float b_[4] = {bq.x, bq.y, bq.z, bq.w};
#pragma unroll
            for (int i = 0; i < 4; ++i)
#pragma unroll
                for (int j = 0; j < 4; ++j)
                    acc[i][j] = fmaf(a_[i], b_[j], acc[i][j]);
        }
        __syncthreads();
    }

#pragma unroll
    for (int i = 0; i < 4; ++i)
        *(float4*)&zp[((size_t)ks * 64 + ty * 4 + i) * U4_ + n0 + tx * 4] =
            make_float4(acc[i][0], acc[i][1], acc[i][2], acc[i][3]);
}

// ---------------------------------------------------------------------------
// Persistent decoder loop v9. Changes vs r13 (both attack coherent traffic):
//  1. hcprev replaced by t-ROTATING hcbuf[t][64][2048] (+64-float plane pad):
//     BC sc-writes plane t; A-blocks PLAIN-CACHED-read plane t-1 (fresh
//     addresses each step -> no staleness; L2-shared across blocks of an
//     XCD -> 16 MB/step uncached reads become ~4 MB/step cached fetches).
//  2. Split-K 8 -> 4: A slice = 512k x 64 cols (Wcomb LDS slice still
//     128 KB; grid still 256 = 4 ks x 64 nt). zp round-trip halves.
// Flags: [g*32] g<16: zp-done (16 adds each/step); [512+g*32] g<8: h-done;
//        [768+g*32] g<8: ctx-done. A ks<2 waits h; ks>=2 waits ctx.
// ---------------------------------------------------------------------------
__global__ __launch_bounds__(512) void decoder_loop9(
    const float* __restrict__ zemb,   // [3200][4096] (in d_out)
    const float* __restrict__ Wcomb,  // [2048][4096]
    const float* __restrict__ keys,   // [64][50][1024]
    const float* __restrict__ memory, // [64][50][1024]
    const float* __restrict__ c0,
    float* __restrict__ hcbuf,        // [50][HCSTR_] (in d_out; sc-write/plain-read)
    float* __restrict__ zp,           // [4][64][4096] (sc-ops only)
    float* __restrict__ hc_all,       // [64][50][2048] (plain; post-loop)
    unsigned* flags)
{
    __shared__ float Bw[512 * 64];    // 128 KB persistent Wcomb slice
    __shared__ float As[2][32][68];
    __shared__ float hs[1024];
    __shared__ float sc[64];
    __shared__ float al[64];

    const int beta = blockIdx.x;
    const int tid  = threadIdx.x;

    const int nt = beta & 63, ks = beta >> 6;   // 64 col-tiles x 4 k-slices
    const int koff = ks * 512;
    const int c0c  = nt * 64;

    // ---- load persistent Wcomb slice [512 k][64 cols] into LDS ----
    {
        const int k_sub = tid >> 4;          // 0..31
        const int c4    = (tid & 15) * 4;    // 0..60
#pragma unroll
        for (int it = 0; it < 16; ++it) {
            int k = it * 32 + k_sub;
            *(float4*)&Bw[k * 64 + c4] =
                *(const float4*)&Wcomb[(size_t)(koff + k) * U4_ + c0c + c4];
        }
    }

    const int b  = beta;
    const int u2 = tid * 2;
    float creg[2] = {0.f, 0.f};
    if (beta < 64) {
        float2 cv = *(const float2*)&c0[b * U_ + u2];
        creg[0] = cv.x;
        creg[1] = cv.y;
    }
    __syncthreads();

    // phase-A indices: 64 rows x 64 cols, 4x2 micro-tile
    const int tx   = tid & 31;           // col pair tx*2
    const int ty   = tid >> 5;           // 0..15, rows ty*4
    const int srow = tid >> 3;           // 0..63
    const int sk4  = (tid & 7) * 4;      // 0..28

    for (int t = 0; t < T_; ++t) {
        // ---------------- phase A (t>=1): zp = hcbuf[t-1]-slice @ Bw --------
        if (t) {
            {   // wait on producer of my k-half
                const unsigned tgt = 8u * (unsigned)t;
                const unsigned* fb = (ks < 2) ? &flags[512] : &flags[768];
                if (tid < 8) {
                    const unsigned* f = fb + tid * 32;
                    while (scload_u(f) < tgt) __builtin_amdgcn_s_sleep(1);
                }
                __syncthreads();
                cbar();
            }

            float acc[4][2];
#pragma unroll
            for (int i = 0; i < 4; ++i) { acc[i][0] = 0.f; acc[i][1] = 0.f; }

            // plain cached reads of the fresh t-1 plane
            const float* ap = &hcbuf[(size_t)(t - 1) * HCSTR_ + srow * 2048 + koff];
            float4 r1;
            {
                float4 r0 = *(const float4*)&ap[sk4];
                As[0][sk4 + 0][srow] = r0.x;
                As[0][sk4 + 1][srow] = r0.y;
                As[0][sk4 + 2][srow] = r0.z;
                As[0][sk4 + 3][srow] = r0.w;
                r1 = *(const float4*)&ap[32 + sk4];
            }
            __syncthreads();

            for (int kc = 0; kc < 16; ++kc) {
                const int cur = kc & 1;
                const float* bwp = &Bw[(kc * 32) * 64];
#pragma unroll
                for (int kk = 0; kk < 32; ++kk) {
                    float4 af = *(const float4*)&As[cur][kk][ty * 4];
                    float2 bf = *(const float2*)&bwp[kk * 64 + tx * 2];
                    float a_[4] = {af.x, af.y, af.z, af.w};
#pragma unroll
                    for (int i = 0; i < 4; ++i) {
                        acc[i][0] = fmaf(a_[i], bf.x, acc[i][0]);
                        acc[i][1] = fmaf(a_[i], bf.y, acc[i][1]);
                    }
                }
                if (kc < 15) {
                    As[cur ^ 1][sk4 + 0][srow] = r1.x;
                    As[cur ^ 1][sk4 + 1][srow] = r1.y;
                    As[cur ^ 1][sk4 + 2][srow] = r1.z;
                    As[cur ^ 1][sk4 + 3][srow] = r1.w;
                    if (kc < 14)
                        r1 = *(const float4*)&ap[(kc + 2) * 32 + sk4];
                }
                __syncthreads();
            }
#pragma unroll
            for (int i = 0; i < 4; ++i) {
                int m = ty * 4 + i;
                scstore8(&zp[((size_t)ks * 64 + m) * U4_ + c0c + tx * 2],
                         acc[i][0], acc[i][1]);
            }
            vm_drain();
            __syncthreads();
            if (tid == 0) scadd_u(&flags[(beta & 15) * 32]);   // zp group flag
        }

        // ---------------- phase BC: gates + attention (blocks < 64) ---------
        if (beta < 64) {
            if (t) {
                const unsigned tgt = 16u * (unsigned)t;
                if (tid < 16) {
                    const unsigned* f = &flags[tid * 32];
                    while (scload_u(f) < tgt) __builtin_amdgcn_s_sleep(1);
                }
                __syncthreads();
                cbar();
            }

            const float* ze = &zemb[((size_t)b * T_ + t) * U4_];
            float zgx[4], zgy[4];
#pragma unroll
            for (int g = 0; g < 4; ++g) {
                float2 a = *(const float2*)&ze[g * U_ + u2];   // plain cached
                zgx[g] = a.x;
                zgy[g] = a.y;
            }
#pragma unroll
            for (int s = 0; s < 4; ++s) {
#pragma unroll
                for (int g = 0; g < 4; ++g) {
                    float2 v = scload8(&zp[((size_t)s * 64 + b) * U4_ + g * U_ + u2]);
                    zgx[g] += v.x;
                    zgy[g] += v.y;
                }
            }

            const float six = 1.f / (1.f + expf(-zgx[0]));
            const float sfx = 1.f / (1.f + expf(-zgx[1]));
            const float tgx = tanhf(zgx[2]);
            const float sox = 1.f / (1.f + expf(-zgx[3]));
            const float cnx = sfx * creg[0] + six * tgx;
            creg[0] = cnx;
            const float hnx = sox * tanhf(cnx);

            const float siy = 1.f / (1.f + expf(-zgy[0]));
            const float sfy = 1.f / (1.f + expf(-zgy[1]));
            const float tgy = tanhf(zgy[2]);
            const float soy = 1.f / (1.f + expf(-zgy[3]));
            const float cny = sfy * creg[1] + siy * tgy;
            creg[1] = cny;
            const float hny = soy * tanhf(cny);

            float* hcb_t = &hcbuf[(size_t)t * HCSTR_];
            hs[u2]     = hnx;
            hs[u2 + 1] = hny;
            scstore8(&hcb_t[b * 2048 + u2], hnx, hny);      // publish (sc)
            *(float2*)&hc_all[((size_t)b * T_ + t) * 2048 + u2] =
                make_float2(hnx, hny);                       // archive (plain)
            vm_drain();
            __syncthreads();
            if (tid == 0) scadd_u(&flags[512 + (b & 7) * 32]);  // h group flag

            // scores (keys plain cached, L2-resident)
            const int lane = tid & 63, w = tid >> 6;
            for (int s = w; s < S_; s += 8) {
                const float* kp = &keys[((size_t)b * S_ + s) * U_ + lane * 16];
                const float* hp = &hs[lane * 16];
                float p = 0.f;
#pragma unroll
                for (int q = 0; q < 4; ++q) {
                    float4 kv = *(const float4*)&kp[q * 4];
                    float4 hv = *(const float4*)&hp[q * 4];
                    p = fmaf(hv.x, kv.x, p);
                    p = fmaf(hv.y, kv.y, p);
                    p = fmaf(hv.z, kv.z, p);
                    p = fmaf(hv.w, kv.w, p);
                }
#pragma unroll
                for (int off = 32; off > 0; off >>= 1)
                    p += __shfl_xor(p, off);
                if (lane == 0) sc[s] = p;
            }
            __syncthreads();

            if (tid < 64) {
                float v = (tid < S_) ? sc[tid] : -INFINITY;
                float m = v;
#pragma unroll
                for (int off = 32; off > 0; off >>= 1)
                    m = fmaxf(m, __shfl_xor(m, off));
                float e = (tid < S_) ? expf(v - m) : 0.f;
                float ssum = e;
#pragma unroll
                for (int off = 32; off > 0; off >>= 1)
                    ssum += __shfl_xor(ssum, off);
                if (tid < S_) al[tid] = e / ssum;
            }
            __syncthreads();

            // ctx (memory plain cached, L2-resident)
            {
                const float2* mp = (const float2*)&memory[(size_t)b * S_ * U_];
                float cx = 0.f, cy = 0.f;
#pragma unroll 10
                for (int s = 0; s < S_; ++s) {
                    float2 mv = mp[s * 512 + tid];
                    const float a = al[s];
                    cx = fmaf(a, mv.x, cx);
                    cy = fmaf(a, mv.y, cy);
                }
                scstore8(&hcb_t[b * 2048 + U_ + u2], cx, cy);
                *(float2*)&hc_all[((size_t)b * T_ + t) * 2048 + U_ + u2] =
                    make_float2(cx, cy);
            }
            vm_drain();
            __syncthreads();
            if (tid == 0) scadd_u(&flags[768 + (b & 7) * 32]);  // ctx group flag
        }
    }
}

// ---------------------------------------------------------------------------
// bf16 MFMA GEMM: C[3200][V] = A[3200][1024] @ B[1024][VP_] + bias.
// ---------------------------------------------------------------------------
__global__ __launch_bounds__(256) void gemm_wo_mfma(
    const bf16_t* __restrict__ A,
    const bf16_t* __restrict__ Bw,
    const float*  __restrict__ bias,
    float* __restrict__ C)
{
    __shared__ bf16_t As[128][40];
    __shared__ bf16_t Bs[128][40];

    const int n0  = blockIdx.x * 128;
    const int m0  = blockIdx.y * 128;
    const int tid = threadIdx.x;
    const int wave = tid >> 6, lane = tid & 63;
    const int wr = wave >> 1, wc = wave & 1;
    const int lr = lane & 15;
    const int lk = lane >> 4;

    f32x4 acc[4][4] = {};

    const int ar = tid >> 1;
    const int ak = (tid & 1) * 16;
    const int bk = tid >> 3;
    const int bn = (tid & 7) * 16;

    for (int k0 = 0; k0 < U_; k0 += 32) {
        {
            const bf16_t* ap = &A[(size_t)(m0 + ar) * U_ + k0 + ak];
            *(bf16x8*)&As[ar][ak]     = *(const bf16x8*)ap;
            *(bf16x8*)&As[ar][ak + 8] = *(const bf16x8*)(ap + 8);
        }
        {
            const bf16_t* bp = &Bw[(size_t)(k0 + bk) * VP_ + n0 + bn];
            bf16x8 v0 = *(const bf16x8*)bp;
            bf16x8 v1 = *(const bf16x8*)(bp + 8);
#pragma unroll
            for (int i = 0; i < 8; ++i) Bs[bn + i][bk] = v0[i];
#pragma unroll
            for (int i = 0; i < 8; ++i) Bs[bn + 8 + i][bk] = v1[i];
        }
        __syncthreads();

        bf16x8 af[4], bf[4];
#pragma unroll
        for (int m = 0; m < 4; ++m)
            af[m] = *(const bf16x8*)&As[wr * 64 + m * 16 + lr][lk * 8];
#pragma unroll
        for (int n = 0; n < 4; ++n)
            bf[n] = *(const bf16x8*)&Bs[wc * 64 + n * 16 + lr][lk * 8];
#pragma unroll
        for (int m = 0; m < 4; ++m)
#pragma unroll
            for (int n = 0; n < 4; ++n)
                acc[m][n] = __builtin_amdgcn_mfma_f32_16x16x32_bf16(
                    af[m], bf[n], acc[m][n], 0, 0, 0);
        __syncthreads();
    }

#pragma unroll
    for (int m = 0; m < 4; ++m) {
        const int row = m0 + wr * 64 + m * 16 + lk * 4;
#pragma unroll
        for (int n = 0; n < 4; ++n) {
            const int col = n0 + wc * 64 + n * 16 + lr;
            if (col < V_) {
                const float bb = bias[col];
#pragma unroll
                for (int r = 0; r < 4; ++r)
                    C[(size_t)(row + r) * V_ + col] = acc[m][n][r] + bb;
            }
        }
    }
}

// ---------------------------------------------------------------------------
extern "C" void kernel_launch(void* const* d_in, const int* in_sizes, int n_in,
                              void* d_out, int out_size, void* d_ws, size_t ws_size,
                              hipStream_t stream)
{
    const int*   tokens = (const int*)  d_in[0];
    const float* memory = (const float*)d_in[1];
    const float* h0     = (const float*)d_in[2];
    const float* c0     = (const float*)d_in[3];
    const float* emb    = (const float*)d_in[4];
    const float* Wx     = (const float*)d_in[5];
    const float* Uh     = (const float*)d_in[6];
    const float* bvec   = (const float*)d_in[7];
    const float* Wm     = (const float*)d_in[8];
    const float* Wa     = (const float*)d_in[9];
    const float* Wo     = (const float*)d_in[10];
    const float* bo     = (const float*)d_in[11];
    float* out = (float*)d_out;

    // ---- workspace layout (float units) ----
    float* ws = (float*)d_ws;
    size_t off = 0;
    float*   Wcomb  = ws + off; off += (size_t)2048 * U4_;      // 33.55 MB
    float*   keys   = ws + off; off += (size_t)B_ * S_ * U_;    // 13.11 MB
    float*   hc_all = ws + off; off += (size_t)B_ * T_ * 2048;  // 26.21 MB
    float*   zp     = ws + off; off += (size_t)4 * B_ * U4_;    //  4.19 MB
    float*   x_emb  = ws + off; off += (size_t)B_ * T_ * E_;    //  1.28 MB
    unsigned* flags = (unsigned*)(ws + off); off += 1024;       //  4 KB
    bf16_t*  wo_bf  = (bf16_t*)(ws + off); off += (size_t)1024 * VP_ / 2; // 61.6 MB
    const size_t need_bytes = off * sizeof(float);

    // d_out-resident scratch (all dead before the final GEMM writes out):
    float* zemb  = out;                           // [3200][4096]   52.4 MB
    float* hcbuf = out + (size_t)3200 * U4_;      // [50][HCSTR_]   26.2 MB
    float*  attn_all = Wcomb;                     // post-loop aliases
    bf16_t* abf      = (bf16_t*)(Wcomb + (size_t)B_ * T_ * U_);

    const bool use_mfma = (ws_size >= need_bytes);

    (void)hipMemsetAsync(flags, 0, 1024 * sizeof(unsigned), stream);

    // ---- pre-loop ----
    gather_emb<<<B_ * T_, 128, 0, stream>>>(tokens, emb, x_emb);
    gemm128<<<dim3(32, 25), 256, 0, stream>>>(
        x_emb, E_, Wx, U4_, zemb, U4_, U4_, E_, bvec);
    gemm128<<<dim3(32, 16), 256, 0, stream>>>(
        Wa, U_, Wx + (size_t)E_ * U4_, U4_, Wcomb, U4_, U4_, U_, nullptr);
    add_inplace<<<(1024 * U4_) / 256, 256, 0, stream>>>(Wcomb, Uh, 1024 * U4_);
    gemm128<<<dim3(8, 25), 256, 0, stream>>>(
        memory, U_, Wm, U_, keys, U_, U_, U_, nullptr);
    zgemm_partial<<<dim3(64, 4), 256, 0, stream>>>(h0, U_, Uh, zp);
    if (use_mfma)
        cast_wo_bf16<<<dim3((VP_ + 255) / 256, 1024), 256, 0, stream>>>(Wo, wo_bf);

    // ---- persistent recurrent loop ----
    decoder_loop9<<<256, 512, 0, stream>>>(
        zemb, Wcomb, keys, memory, c0, hcbuf, zp, hc_all, flags);

    // ---- post-loop ----
    gemm128<<<dim3(8, 25), 256, 0, stream>>>(
        hc_all, 2048, Wa, U_, attn_all, U_, U_, 2048, nullptr);

    if (use_mfma) {
        cast_bf16<<<2048, 256, 0, stream>>>(attn_all, abf, B_ * T_ * U_);
        gemm_wo_mfma<<<dim3(VP_ / 128, 25), 256, 0, stream>>>(abf, wo_bf, bo, out);
    } else {
        gemm128<<<dim3(235, 25), 256, 0, stream>>>(
            attn_all, U_, Wo, V_, out, V_, V_, U_, bo);
    }
}

// Round 15
// 2978.463 us; speedup vs baseline: 2.3212x; 1.1660x over previous
//
#include <hip/hip_runtime.h>
#include <math.h>

#define B_  64
#define T_  50
#define S_  50
#define U_  1024
#define E_  100
#define V_  30001
#define U4_ 4096
#define VP_ 30080       // V padded to a multiple of 128 for bf16 staging
#define HCSTR_ 131136   // hcbuf plane stride: 64*2048 + 64 pad floats

typedef __bf16 bf16_t;
typedef bf16_t bf16x8 __attribute__((ext_vector_type(8)));
typedef float  f32x4  __attribute__((ext_vector_type(4)));
typedef unsigned long long u64_t;

// ---------------------------------------------------------------------------
// Coherence-point accessors (SYSTEM scope -> sc0+sc1; proven r11-r14).
// ---------------------------------------------------------------------------
__device__ __forceinline__ float2 scload8(const float* p) {
    u64_t v = __hip_atomic_load((const u64_t*)p, __ATOMIC_RELAXED,
                                __HIP_MEMORY_SCOPE_SYSTEM);
    union { u64_t u; float2 f; } c; c.u = v; return c.f;
}
__device__ __forceinline__ void scstore8(float* p, float x, float y) {
    union { u64_t u; float2 f; } c; c.f = make_float2(x, y);
    __hip_atomic_store((u64_t*)p, c.u, __ATOMIC_RELAXED,
                       __HIP_MEMORY_SCOPE_SYSTEM);
}
__device__ __forceinline__ unsigned scload_u(const unsigned* p) {
    return __hip_atomic_load(p, __ATOMIC_RELAXED, __HIP_MEMORY_SCOPE_SYSTEM);
}
__device__ __forceinline__ void scadd_u(unsigned* p) {
    __hip_atomic_fetch_add(p, 1u, __ATOMIC_RELAXED, __HIP_MEMORY_SCOPE_SYSTEM);
}
__device__ __forceinline__ void vm_drain() {
    asm volatile("s_waitcnt vmcnt(0)" ::: "memory");
}
__device__ __forceinline__ void cbar() { asm volatile("" ::: "memory"); }

// ---------------------------------------------------------------------------
// Generic tiled f32 GEMM (pre/post-loop).
// ---------------------------------------------------------------------------
__global__ __launch_bounds__(256) void gemm128(
    const float* __restrict__ A, int lda,
    const float* __restrict__ Bm, int ldb,
    float* __restrict__ C, int ldc,
    int N, int K, const float* __restrict__ bias)
{
    __shared__ float As[8][132];
    __shared__ float Bs[8][132];

    const int n0  = blockIdx.x * 128;
    const int m0  = blockIdx.y * 128;
    const int tid = threadIdx.x;
    const int tx  = tid & 15, ty = tid >> 4;

    float acc[8][8];
#pragma unroll
    for (int i = 0; i < 8; ++i)
#pragma unroll
        for (int j = 0; j < 8; ++j) acc[i][j] = 0.f;

    const int ra = tid >> 1, ca = (tid & 1) * 4;
    const int rb = tid >> 5, cb = (tid & 31) * 4;
    const bool fast_b = ((ldb & 3) == 0) && (n0 + 128 <= N);

    for (int k0 = 0; k0 < K; k0 += 8) {
        const float* ap = &A[(size_t)(m0 + ra) * lda + k0 + ca];
        float4 av;
        if (k0 + 8 <= K) {
            av = *(const float4*)ap;
        } else {
            av.x = (k0 + ca + 0 < K) ? ap[0] : 0.f;
            av.y = (k0 + ca + 1 < K) ? ap[1] : 0.f;
            av.z = (k0 + ca + 2 < K) ? ap[2] : 0.f;
            av.w = (k0 + ca + 3 < K) ? ap[3] : 0.f;
        }
        As[ca + 0][ra] = av.x;
        As[ca + 1][ra] = av.y;
        As[ca + 2][ra] = av.z;
        As[ca + 3][ra] = av.w;

        float4 bv = make_float4(0.f, 0.f, 0.f, 0.f);
        if (k0 + rb < K) {
            const float* bp = &Bm[(size_t)(k0 + rb) * ldb];
            if (fast_b) {
                bv = *(const float4*)&bp[n0 + cb];
            } else {
                bv.x = (n0 + cb + 0 < N) ? bp[n0 + cb + 0] : 0.f;
                bv.y = (n0 + cb + 1 < N) ? bp[n0 + cb + 1] : 0.f;
                bv.z = (n0 + cb + 2 < N) ? bp[n0 + cb + 2] : 0.f;
                bv.w = (n0 + cb + 3 < N) ? bp[n0 + cb + 3] : 0.f;
            }
        }
        *(float4*)&Bs[rb][cb] = bv;
        __syncthreads();

#pragma unroll
        for (int kk = 0; kk < 8; ++kk) {
            float4 a0 = *(const float4*)&As[kk][ty * 4];
            float4 a1 = *(const float4*)&As[kk][64 + ty * 4];
            float4 b0 = *(const float4*)&Bs[kk][tx * 4];
            float4 b1 = *(const float4*)&Bs[kk][64 + tx * 4];
            float a_[8] = {a0.x, a0.y, a0.z, a0.w, a1.x, a1.y, a1.z, a1.w};
            float b_[8] = {b0.x, b0.y, b0.z, b0.w, b1.x, b1.y, b1.z, b1.w};
#pragma unroll
            for (int i = 0; i < 8; ++i)
#pragma unroll
                for (int j = 0; j < 8; ++j)
                    acc[i][j] = fmaf(a_[i], b_[j], acc[i][j]);
        }
        __syncthreads();
    }

#pragma unroll
    for (int i = 0; i < 8; ++i) {
        int row = m0 + ((i < 4) ? (ty * 4 + i) : (64 + ty * 4 + (i - 4)));
#pragma unroll
        for (int j = 0; j < 8; ++j) {
            int col = n0 + ((j < 4) ? (tx * 4 + j) : (64 + tx * 4 + (j - 4)));
            if (col < N) {
                float v = acc[i][j];
                if (bias) v += bias[col];
                C[(size_t)row * ldc + col] = v;
            }
        }
    }
}

__global__ void add_inplace(float* __restrict__ dst, const float* __restrict__ src, int n)
{
    int i = blockIdx.x * blockDim.x + threadIdx.x;
    if (i < n) dst[i] += src[i];
}

__global__ void gather_emb(const int* __restrict__ tokens,
                           const float* __restrict__ emb,
                           float* __restrict__ xe)
{
    const int r = blockIdx.x;
    const int e = threadIdx.x;
    if (e < E_) xe[(size_t)r * E_ + e] = emb[(size_t)tokens[r] * E_ + e];
}

__global__ void cast_bf16(const float* __restrict__ src, bf16_t* __restrict__ dst, int n)
{
    int i = blockIdx.x * blockDim.x + threadIdx.x;
    const int stride = gridDim.x * blockDim.x;
    for (; i < n; i += stride) dst[i] = (bf16_t)src[i];
}

__global__ void cast_wo_bf16(const float* __restrict__ wo, bf16_t* __restrict__ dst)
{
    const int col = blockIdx.x * 256 + threadIdx.x;
    const int k   = blockIdx.y;
    if (col < VP_)
        dst[(size_t)k * VP_ + col] =
            (col < V_) ? (bf16_t)wo[(size_t)k * V_ + col] : (bf16_t)0.f;
}

// ---------------------------------------------------------------------------
// Split-K GEMM for t=0: zp[(ks*64+b)*4096+n] = sum_{k in 256-slice} h0@Uh.
// ---------------------------------------------------------------------------
__global__ __launch_bounds__(256) void zgemm_partial(
    const float* __restrict__ A, int lda,
    const float* __restrict__ Bm,
    float* __restrict__ zp)
{
    __shared__ float As[64][17];
    __shared__ float Bs[16][68];

    const int n0     = blockIdx.x * 64;
    const int ks     = blockIdx.y;
    const int k_base = ks * 256;
    const int tid    = threadIdx.x;
    const int tx     = tid & 15, ty = tid >> 4;

    float acc[4][4];
#pragma unroll
    for (int i = 0; i < 4; ++i)
#pragma unroll
        for (int j = 0; j < 4; ++j) acc[i][j] = 0.f;

    const int ra = tid >> 2, ca = (tid & 3) * 4;
    const int rb = tid >> 4, cb = (tid & 15) * 4;

    for (int kt = 0; kt < 16; ++kt) {
        const int k0 = k_base + kt * 16;
        float4 av = *(const float4*)&A[(size_t)ra * lda + k0 + ca];
        As[ra][ca + 0] = av.x;
        As[ra][ca + 1] = av.y;
        As[ra][ca + 2] = av.z;
        As[ra][ca + 3] = av.w;
        float4 bv = *(const float4*)&Bm[(size_t)(k0 + rb) * U4_ + n0 + cb];
        *(float4*)&Bs[rb][cb] = bv;
        __syncthreads();
#pragma unroll
        for (int kk = 0; kk < 16; ++kk) {
            float a_[4];
#pragma unroll
            for (int i = 0; i < 4; ++i) a_[i] = As[ty * 4 + i][kk];
            float4 bq = *(const float4*)&Bs[kk][tx * 4];
            float b_[4] = {bq.x, bq.y, bq.z, bq.w};
#pragma unroll
            for (int i = 0; i < 4; ++i)
#pragma unroll
                for (int j = 0; j < 4; ++j)
                    acc[i][j] = fmaf(a_[i], b_[j], acc[i][j]);
        }
        __syncthreads();
    }

#pragma unroll
    for (int i = 0; i < 4; ++i)
        *(float4*)&zp[((size_t)ks * 64 + ty * 4 + i) * U4_ + n0 + tx * 4] =
            make_float4(acc[i][0], acc[i][1], acc[i][2], acc[i][3]);
}

// ---------------------------------------------------------------------------
// Persistent decoder loop v10 = r14 structure with phase A on MATRIX CORES.
// Split-bf16 3-pass MFMA: z = Ah@Bh + Ah@Bl + Al@Bh (rel err ~2^-18, safe
// in the recurrence — unlike r7's direct bf16 state at 4e-3).
//  * Wcomb slice packed ONCE per block (t=0) into LDS in per-lane fragment
//    order (hi/lo bf16, 128 KB, linear bf16x8 reads).
//  * State A chunk [64 rows][32 k] staged per kk into small dbuf LDS tile
//    (XOR-swizzled), split hi/lo in registers.
//  * Fragment maps identical to the VERIFIED gemm_wo_mfma.
//  * zp written via LDS transpose -> 8B sc-stores (vectorized, r12 lesson).
// Everything else (flags, hcbuf rotation, BC) byte-identical to r14.
// LDS: wfr 131072 + lA 18432 (aliased by tr 17408) + hs 4096 + sc/al 512
//    = 154112 B.
// ---------------------------------------------------------------------------
__global__ __launch_bounds__(512) void decoder_loop10(
    const float* __restrict__ zemb,   // [3200][4096] (in d_out)
    const float* __restrict__ Wcomb,  // [2048][4096]
    const float* __restrict__ keys,   // [64][50][1024]
    const float* __restrict__ memory, // [64][50][1024]
    const float* __restrict__ c0,
    float* __restrict__ hcbuf,        // [50][HCSTR_] (in d_out)
    float* __restrict__ zp,           // [4][64][4096] (sc-ops only)
    float* __restrict__ hc_all,       // [64][50][2048] (plain)
    unsigned* flags)
{
    static __shared__ __attribute__((aligned(16))) char smem[154112];
    bf16_t* wfr = (bf16_t*)smem;                    // 131072 B frag store
    float*  lA  = (float*)(smem + 131072);          // [2][2304] staging
    float*  tr  = (float*)(smem + 131072);          // [64][68] (alias)
    float*  hs  = (float*)(smem + 149504);          // 1024
    float*  sc  = (float*)(smem + 153600);          // 64
    float*  al  = (float*)(smem + 153856);          // 64

    const int beta = blockIdx.x;
    const int tid  = threadIdx.x;

    const int nt = beta & 63, ks = beta >> 6;
    const int koff = ks * 512;
    const int c0c  = nt * 64;

    // ---- pack Wcomb slice [512 k][64 cols] -> LDS fragments (once) ----
    for (int i = tid; i < 512 * 64; i += 512) {
        const int k = i >> 6, col = i & 63;
        const float w = Wcomb[(size_t)(koff + k) * U4_ + c0c + col];
        const bf16_t hi = (bf16_t)w;
        const bf16_t lo = (bf16_t)(w - (float)hi);
        const int ntile = col >> 4, lane_lo = col & 15;
        const int kk = k >> 5, kr = k & 31;
        const int lane = (kr >> 3) * 16 + lane_lo, j = kr & 7;
        const int base = ((ntile * 16 + kk) * 2) * 512 + lane * 8 + j;
        wfr[base]       = hi;
        wfr[base + 512] = lo;
    }

    const int b  = beta;
    const int u2 = tid * 2;
    float creg[2] = {0.f, 0.f};
    if (beta < 64) {
        float2 cv = *(const float2*)&c0[b * U_ + u2];
        creg[0] = cv.x;
        creg[1] = cv.y;
    }
    __syncthreads();

    // phase-A indices
    const int w    = tid >> 6, l = tid & 63;
    const int mt   = w >> 1, ntb = (w & 1) * 2;
    const int arow = mt * 16 + (l & 15);
    const int aq   = l >> 4;
    const int aphys = arow * 36 + (((aq ^ (arow & 3)) & 3) << 3);
    // staging indices: chunk [64 rows][32 k], 1 float4/thread
    const int sr = tid >> 3, sc4 = (tid & 7) * 4;
    const int sq = sc4 >> 3, srem = sc4 & 7;
    const int sphys = sr * 36 + (((sq ^ (sr & 3)) & 3) << 3) + srem;

    for (int t = 0; t < T_; ++t) {
        // ---------------- phase A (t>=1): zp = hcbuf[t-1] @ Wcomb (MFMA) ----
        if (t) {
            {   // wait on producer of my k-half
                const unsigned tgt = 8u * (unsigned)t;
                const unsigned* fb = (ks < 2) ? &flags[512] : &flags[768];
                if (tid < 8) {
                    const unsigned* f = fb + tid * 32;
                    while (scload_u(f) < tgt) __builtin_amdgcn_s_sleep(1);
                }
                __syncthreads();
                cbar();
            }

            const float* apbase = &hcbuf[(size_t)(t - 1) * HCSTR_];
            // stage chunk 0
            {
                float4 av = *(const float4*)&apbase[(size_t)sr * 2048 + koff + sc4];
                *(float4*)&lA[sphys] = av;
            }
            __syncthreads();

            f32x4 acc[2] = {};
            for (int kk = 0; kk < 16; ++kk) {
                const int cur = kk & 1;
                float4 pre;
                if (kk < 15)
                    pre = *(const float4*)&apbase[(size_t)sr * 2048 + koff + (kk + 1) * 32 + sc4];

                // A fragment from LDS chunk -> hi/lo bf16
                const float* Ab = &lA[cur * 2304];
                float4 a0 = *(const float4*)&Ab[aphys];
                float4 a1 = *(const float4*)&Ab[aphys + 4];
                float xs[8] = {a0.x, a0.y, a0.z, a0.w, a1.x, a1.y, a1.z, a1.w};
                bf16x8 ah, alv;
#pragma unroll
                for (int e = 0; e < 8; ++e) {
                    bf16_t h = (bf16_t)xs[e];
                    ah[e]  = h;
                    alv[e] = (bf16_t)(xs[e] - (float)h);
                }
#pragma unroll
                for (int nn = 0; nn < 2; ++nn) {
                    const int fb2 = (((ntb + nn) * 16 + kk) * 2) * 512 + l * 8;
                    bf16x8 bh = *(const bf16x8*)&wfr[fb2];
                    bf16x8 bl = *(const bf16x8*)&wfr[fb2 + 512];
                    acc[nn] = __builtin_amdgcn_mfma_f32_16x16x32_bf16(ah, bh, acc[nn], 0, 0, 0);
                    acc[nn] = __builtin_amdgcn_mfma_f32_16x16x32_bf16(ah, bl, acc[nn], 0, 0, 0);
                    acc[nn] = __builtin_amdgcn_mfma_f32_16x16x32_bf16(alv, bh, acc[nn], 0, 0, 0);
                }
                if (kk < 15) {
                    *(float4*)&lA[(cur ^ 1) * 2304 + sphys] = pre;
                    __syncthreads();
                }
            }
            __syncthreads();   // all lA reads done (tr aliases lA)

            // acc -> LDS transpose (C/D map: col=l&15, row=(l>>4)*4+reg)
#pragma unroll
            for (int nn = 0; nn < 2; ++nn)
#pragma unroll
                for (int rr = 0; rr < 4; ++rr)
                    tr[(mt * 16 + (l >> 4) * 4 + rr) * 68 + (ntb + nn) * 16 + (l & 15)] =
                        acc[nn][rr];
            __syncthreads();

            // vectorized sc-stores of zp
            {
                const int zb = tid >> 3, cg = (tid & 7) * 8;
                float4 r0 = *(const float4*)&tr[zb * 68 + cg];
                float4 r1 = *(const float4*)&tr[zb * 68 + cg + 4];
                float* zrow = &zp[((size_t)(ks * 64 + zb)) * U4_ + c0c + cg];
                scstore8(zrow + 0, r0.x, r0.y);
                scstore8(zrow + 2, r0.z, r0.w);
                scstore8(zrow + 4, r1.x, r1.y);
                scstore8(zrow + 6, r1.z, r1.w);
            }
            vm_drain();
            __syncthreads();
            if (tid == 0) scadd_u(&flags[(beta & 15) * 32]);   // zp group flag
        }

        // ---------------- phase BC: gates + attention (blocks < 64) ---------
        if (beta < 64) {
            if (t) {
                const unsigned tgt = 16u * (unsigned)t;
                if (tid < 16) {
                    const unsigned* f = &flags[tid * 32];
                    while (scload_u(f) < tgt) __builtin_amdgcn_s_sleep(1);
                }
                __syncthreads();
                cbar();
            }

            const float* ze = &zemb[((size_t)b * T_ + t) * U4_];
            float zgx[4], zgy[4];
#pragma unroll
            for (int g = 0; g < 4; ++g) {
                float2 a = *(const float2*)&ze[g * U_ + u2];   // plain cached
                zgx[g] = a.x;
                zgy[g] = a.y;
            }
#pragma unroll
            for (int s = 0; s < 4; ++s) {
#pragma unroll
                for (int g = 0; g < 4; ++g) {
                    float2 v = scload8(&zp[((size_t)s * 64 + b) * U4_ + g * U_ + u2]);
                    zgx[g] += v.x;
                    zgy[g] += v.y;
                }
            }

            const float six = 1.f / (1.f + expf(-zgx[0]));
            const float sfx = 1.f / (1.f + expf(-zgx[1]));
            const float tgx = tanhf(zgx[2]);
            const float sox = 1.f / (1.f + expf(-zgx[3]));
            const float cnx = sfx * creg[0] + six * tgx;
            creg[0] = cnx;
            const float hnx = sox * tanhf(cnx);

            const float siy = 1.f / (1.f + expf(-zgy[0]));
            const float sfy = 1.f / (1.f + expf(-zgy[1]));
            const float tgy = tanhf(zgy[2]);
            const float soy = 1.f / (1.f + expf(-zgy[3]));
            const float cny = sfy * creg[1] + siy * tgy;
            creg[1] = cny;
            const float hny = soy * tanhf(cny);

            float* hcb_t = &hcbuf[(size_t)t * HCSTR_];
            hs[u2]     = hnx;
            hs[u2 + 1] = hny;
            scstore8(&hcb_t[b * 2048 + u2], hnx, hny);      // publish (sc)
            *(float2*)&hc_all[((size_t)b * T_ + t) * 2048 + u2] =
                make_float2(hnx, hny);                       // archive (plain)
            vm_drain();
            __syncthreads();
            if (tid == 0) scadd_u(&flags[512 + (b & 7) * 32]);  // h group flag

            // scores (keys plain cached, L2-resident)
            const int lane = tid & 63, wv = tid >> 6;
            for (int s = wv; s < S_; s += 8) {
                const float* kp = &keys[((size_t)b * S_ + s) * U_ + lane * 16];
                const float* hp = &hs[lane * 16];
                float p = 0.f;
#pragma unroll
                for (int q = 0; q < 4; ++q) {
                    float4 kv = *(const float4*)&kp[q * 4];
                    float4 hv = *(const float4*)&hp[q * 4];
                    p = fmaf(hv.x, kv.x, p);
                    p = fmaf(hv.y, kv.y, p);
                    p = fmaf(hv.z, kv.z, p);
                    p = fmaf(hv.w, kv.w, p);
                }
#pragma unroll
                for (int off = 32; off > 0; off >>= 1)
                    p += __shfl_xor(p, off);
                if (lane == 0) sc[s] = p;
            }
            __syncthreads();

            if (tid < 64) {
                float v = (tid < S_) ? sc[tid] : -INFINITY;
                float m = v;
#pragma unroll
                for (int off = 32; off > 0; off >>= 1)
                    m = fmaxf(m, __shfl_xor(m, off));
                float e = (tid < S_) ? expf(v - m) : 0.f;
                float ssum = e;
#pragma unroll
                for (int off = 32; off > 0; off >>= 1)
                    ssum += __shfl_xor(ssum, off);
                if (tid < S_) al[tid] = e / ssum;
            }
            __syncthreads();

            // ctx (memory plain cached, L2-resident)
            {
                const float2* mp = (const float2*)&memory[(size_t)b * S_ * U_];
                float cx = 0.f, cy = 0.f;
#pragma unroll 10
                for (int s = 0; s < S_; ++s) {
                    float2 mv = mp[s * 512 + tid];
                    const float a = al[s];
                    cx = fmaf(a, mv.x, cx);
                    cy = fmaf(a, mv.y, cy);
                }
                scstore8(&hcb_t[b * 2048 + U_ + u2], cx, cy);
                *(float2*)&hc_all[((size_t)b * T_ + t) * 2048 + U_ + u2] =
                    make_float2(cx, cy);
            }
            vm_drain();
            __syncthreads();
            if (tid == 0) scadd_u(&flags[768 + (b & 7) * 32]);  // ctx group flag
        }
    }
}

// ---------------------------------------------------------------------------
// bf16 MFMA GEMM: C[3200][V] = A[3200][1024] @ B[1024][VP_] + bias.
// ---------------------------------------------------------------------------
__global__ __launch_bounds__(256) void gemm_wo_mfma(
    const bf16_t* __restrict__ A,
    const bf16_t* __restrict__ Bw,
    const float*  __restrict__ bias,
    float* __restrict__ C)
{
    __shared__ bf16_t As[128][40];
    __shared__ bf16_t Bs[128][40];

    const int n0  = blockIdx.x * 128;
    const int m0  = blockIdx.y * 128;
    const int tid = threadIdx.x;
    const int wave = tid >> 6, lane = tid & 63;
    const int wr = wave >> 1, wc = wave & 1;
    const int lr = lane & 15;
    const int lk = lane >> 4;

    f32x4 acc[4][4] = {};

    const int ar = tid >> 1;
    const int ak = (tid & 1) * 16;
    const int bk = tid >> 3;
    const int bn = (tid & 7) * 16;

    for (int k0 = 0; k0 < U_; k0 += 32) {
        {
            const bf16_t* ap = &A[(size_t)(m0 + ar) * U_ + k0 + ak];
            *(bf16x8*)&As[ar][ak]     = *(const bf16x8*)ap;
            *(bf16x8*)&As[ar][ak + 8] = *(const bf16x8*)(ap + 8);
        }
        {
            const bf16_t* bp = &Bw[(size_t)(k0 + bk) * VP_ + n0 + bn];
            bf16x8 v0 = *(const bf16x8*)bp;
            bf16x8 v1 = *(const bf16x8*)(bp + 8);
#pragma unroll
            for (int i = 0; i < 8; ++i) Bs[bn + i][bk] = v0[i];
#pragma unroll
            for (int i = 0; i < 8; ++i) Bs[bn + 8 + i][bk] = v1[i];
        }
        __syncthreads();

        bf16x8 af[4], bf[4];
#pragma unroll
        for (int m = 0; m < 4; ++m)
            af[m] = *(const bf16x8*)&As[wr * 64 + m * 16 + lr][lk * 8];
#pragma unroll
        for (int n = 0; n < 4; ++n)
            bf[n] = *(const bf16x8*)&Bs[wc * 64 + n * 16 + lr][lk * 8];
#pragma unroll
        for (int m = 0; m < 4; ++m)
#pragma unroll
            for (int n = 0; n < 4; ++n)
                acc[m][n] = __builtin_amdgcn_mfma_f32_16x16x32_bf16(
                    af[m], bf[n], acc[m][n], 0, 0, 0);
        __syncthreads();
    }

#pragma unroll
    for (int m = 0; m < 4; ++m) {
        const int row = m0 + wr * 64 + m * 16 + lk * 4;
#pragma unroll
        for (int n = 0; n < 4; ++n) {
            const int col = n0 + wc * 64 + n * 16 + lr;
            if (col < V_) {
                const float bb = bias[col];
#pragma unroll
                for (int r = 0; r < 4; ++r)
                    C[(size_t)(row + r) * V_ + col] = acc[m][n][r] + bb;
            }
        }
    }
}

// ---------------------------------------------------------------------------
extern "C" void kernel_launch(void* const* d_in, const int* in_sizes, int n_in,
                              void* d_out, int out_size, void* d_ws, size_t ws_size,
                              hipStream_t stream)
{
    const int*   tokens = (const int*)  d_in[0];
    const float* memory = (const float*)d_in[1];
    const float* h0     = (const float*)d_in[2];
    const float* c0     = (const float*)d_in[3];
    const float* emb    = (const float*)d_in[4];
    const float* Wx     = (const float*)d_in[5];
    const float* Uh     = (const float*)d_in[6];
    const float* bvec   = (const float*)d_in[7];
    const float* Wm     = (const float*)d_in[8];
    const float* Wa     = (const float*)d_in[9];
    const float* Wo     = (const float*)d_in[10];
    const float* bo     = (const float*)d_in[11];
    float* out = (float*)d_out;

    // ---- workspace layout (float units) ----
    float* ws = (float*)d_ws;
    size_t off = 0;
    float*   Wcomb  = ws + off; off += (size_t)2048 * U4_;      // 33.55 MB
    float*   keys   = ws + off; off += (size_t)B_ * S_ * U_;    // 13.11 MB
    float*   hc_all = ws + off; off += (size_t)B_ * T_ * 2048;  // 26.21 MB
    float*   zp     = ws + off; off += (size_t)4 * B_ * U4_;    //  4.19 MB
    float*   x_emb  = ws + off; off += (size_t)B_ * T_ * E_;    //  1.28 MB
    unsigned* flags = (unsigned*)(ws + off); off += 1024;       //  4 KB
    bf16_t*  wo_bf  = (bf16_t*)(ws + off); off += (size_t)1024 * VP_ / 2; // 61.6 MB
    const size_t need_bytes = off * sizeof(float);

    // d_out-resident scratch (all dead before the final GEMM writes out):
    float* zemb  = out;                           // [3200][4096]   52.4 MB
    float* hcbuf = out + (size_t)3200 * U4_;      // [50][HCSTR_]   26.2 MB
    float*  attn_all = Wcomb;                     // post-loop aliases
    bf16_t* abf      = (bf16_t*)(Wcomb + (size_t)B_ * T_ * U_);

    const bool use_mfma = (ws_size >= need_bytes);

    (void)hipMemsetAsync(flags, 0, 1024 * sizeof(unsigned), stream);

    // ---- pre-loop ----
    gather_emb<<<B_ * T_, 128, 0, stream>>>(tokens, emb, x_emb);
    gemm128<<<dim3(32, 25), 256, 0, stream>>>(
        x_emb, E_, Wx, U4_, zemb, U4_, U4_, E_, bvec);
    gemm128<<<dim3(32, 16), 256, 0, stream>>>(
        Wa, U_, Wx + (size_t)E_ * U4_, U4_, Wcomb, U4_, U4_, U_, nullptr);
    add_inplace<<<(1024 * U4_) / 256, 256, 0, stream>>>(Wcomb, Uh, 1024 * U4_);
    gemm128<<<dim3(8, 25), 256, 0, stream>>>(
        memory, U_, Wm, U_, keys, U_, U_, U_, nullptr);
    zgemm_partial<<<dim3(64, 4), 256, 0, stream>>>(h0, U_, Uh, zp);
    if (use_mfma)
        cast_wo_bf16<<<dim3((VP_ + 255) / 256, 1024), 256, 0, stream>>>(Wo, wo_bf);

    // ---- persistent recurrent loop (phase A on MFMA) ----
    decoder_loop10<<<256, 512, 0, stream>>>(
        zemb, Wcomb, keys, memory, c0, hcbuf, zp, hc_all, flags);

    // ---- post-loop ----
    gemm128<<<dim3(8, 25), 256, 0, stream>>>(
        hc_all, 2048, Wa, U_, attn_all, U_, U_, 2048, nullptr);

    if (use_mfma) {
        cast_bf16<<<2048, 256, 0, stream>>>(attn_all, abf, B_ * T_ * U_);
        gemm_wo_mfma<<<dim3(VP_ / 128, 25), 256, 0, stream>>>(abf, wo_bf, bo, out);
    } else {
        gemm128<<<dim3(235, 25), 256, 0, stream>>>(
            attn_all, U_, Wo, V_, out, V_, V_, U_, bo);
    }
}

// Round 16
// 2212.618 us; speedup vs baseline: 3.1247x; 1.3461x over previous
//
#include <hip/hip_runtime.h>
#include <math.h>

#define B_  64
#define T_  50
#define S_  50
#define U_  1024
#define E_  100
#define V_  30001
#define U4_ 4096
#define VP_ 30080       // V padded to a multiple of 128 for bf16 staging
#define HCSTR_ 131136   // hcbuf plane stride: 64*2048 + 64 pad floats

typedef __bf16 bf16_t;
typedef bf16_t bf16x8 __attribute__((ext_vector_type(8)));
typedef float  f32x4  __attribute__((ext_vector_type(4)));
typedef unsigned long long u64_t;

// ---------------------------------------------------------------------------
// Coherence-point accessors (SYSTEM scope -> sc0+sc1; proven r11-r15).
// ---------------------------------------------------------------------------
__device__ __forceinline__ float2 scload8(const float* p) {
    u64_t v = __hip_atomic_load((const u64_t*)p, __ATOMIC_RELAXED,
                                __HIP_MEMORY_SCOPE_SYSTEM);
    union { u64_t u; float2 f; } c; c.u = v; return c.f;
}
__device__ __forceinline__ void scstore8(float* p, float x, float y) {
    union { u64_t u; float2 f; } c; c.f = make_float2(x, y);
    __hip_atomic_store((u64_t*)p, c.u, __ATOMIC_RELAXED,
                       __HIP_MEMORY_SCOPE_SYSTEM);
}
__device__ __forceinline__ unsigned scload_u(const unsigned* p) {
    return __hip_atomic_load(p, __ATOMIC_RELAXED, __HIP_MEMORY_SCOPE_SYSTEM);
}
__device__ __forceinline__ void scadd_u(unsigned* p) {
    __hip_atomic_fetch_add(p, 1u, __ATOMIC_RELAXED, __HIP_MEMORY_SCOPE_SYSTEM);
}
__device__ __forceinline__ void vm_drain() {
    asm volatile("s_waitcnt vmcnt(0)" ::: "memory");
}
__device__ __forceinline__ void cbar() { asm volatile("" ::: "memory"); }

// ---------------------------------------------------------------------------
// Generic tiled f32 GEMM (kept only for zemb, K=100 tail).
// ---------------------------------------------------------------------------
__global__ __launch_bounds__(256) void gemm128(
    const float* __restrict__ A, int lda,
    const float* __restrict__ Bm, int ldb,
    float* __restrict__ C, int ldc,
    int N, int K, const float* __restrict__ bias)
{
    __shared__ float As[8][132];
    __shared__ float Bs[8][132];

    const int n0  = blockIdx.x * 128;
    const int m0  = blockIdx.y * 128;
    const int tid = threadIdx.x;
    const int tx  = tid & 15, ty = tid >> 4;

    float acc[8][8];
#pragma unroll
    for (int i = 0; i < 8; ++i)
#pragma unroll
        for (int j = 0; j < 8; ++j) acc[i][j] = 0.f;

    const int ra = tid >> 1, ca = (tid & 1) * 4;
    const int rb = tid >> 5, cb = (tid & 31) * 4;
    const bool fast_b = ((ldb & 3) == 0) && (n0 + 128 <= N);

    for (int k0 = 0; k0 < K; k0 += 8) {
        const float* ap = &A[(size_t)(m0 + ra) * lda + k0 + ca];
        float4 av;
        if (k0 + 8 <= K) {
            av = *(const float4*)ap;
        } else {
            av.x = (k0 + ca + 0 < K) ? ap[0] : 0.f;
            av.y = (k0 + ca + 1 < K) ? ap[1] : 0.f;
            av.z = (k0 + ca + 2 < K) ? ap[2] : 0.f;
            av.w = (k0 + ca + 3 < K) ? ap[3] : 0.f;
        }
        As[ca + 0][ra] = av.x;
        As[ca + 1][ra] = av.y;
        As[ca + 2][ra] = av.z;
        As[ca + 3][ra] = av.w;

        float4 bv = make_float4(0.f, 0.f, 0.f, 0.f);
        if (k0 + rb < K) {
            const float* bp = &Bm[(size_t)(k0 + rb) * ldb];
            if (fast_b) {
                bv = *(const float4*)&bp[n0 + cb];
            } else {
                bv.x = (n0 + cb + 0 < N) ? bp[n0 + cb + 0] : 0.f;
                bv.y = (n0 + cb + 1 < N) ? bp[n0 + cb + 1] : 0.f;
                bv.z = (n0 + cb + 2 < N) ? bp[n0 + cb + 2] : 0.f;
                bv.w = (n0 + cb + 3 < N) ? bp[n0 + cb + 3] : 0.f;
            }
        }
        *(float4*)&Bs[rb][cb] = bv;
        __syncthreads();

#pragma unroll
        for (int kk = 0; kk < 8; ++kk) {
            float4 a0 = *(const float4*)&As[kk][ty * 4];
            float4 a1 = *(const float4*)&As[kk][64 + ty * 4];
            float4 b0 = *(const float4*)&Bs[kk][tx * 4];
            float4 b1 = *(const float4*)&Bs[kk][64 + tx * 4];
            float a_[8] = {a0.x, a0.y, a0.z, a0.w, a1.x, a1.y, a1.z, a1.w};
            float b_[8] = {b0.x, b0.y, b0.z, b0.w, b1.x, b1.y, b1.z, b1.w};
#pragma unroll
            for (int i = 0; i < 8; ++i)
#pragma unroll
                for (int j = 0; j < 8; ++j)
                    acc[i][j] = fmaf(a_[i], b_[j], acc[i][j]);
        }
        __syncthreads();
    }

#pragma unroll
    for (int i = 0; i < 8; ++i) {
        int row = m0 + ((i < 4) ? (ty * 4 + i) : (64 + ty * 4 + (i - 4)));
#pragma unroll
        for (int j = 0; j < 8; ++j) {
            int col = n0 + ((j < 4) ? (tx * 4 + j) : (64 + tx * 4 + (j - 4)));
            if (col < N) {
                float v = acc[i][j];
                if (bias) v += bias[col];
                C[(size_t)row * ldc + col] = v;
            }
        }
    }
}

__global__ void add_inplace(float* __restrict__ dst, const float* __restrict__ src, int n)
{
    int i = blockIdx.x * blockDim.x + threadIdx.x;
    if (i < n) dst[i] += src[i];
}

__global__ void gather_emb(const int* __restrict__ tokens,
                           const float* __restrict__ emb,
                           float* __restrict__ xe)
{
    const int r = blockIdx.x;
    const int e = threadIdx.x;
    if (e < E_) xe[(size_t)r * E_ + e] = emb[(size_t)tokens[r] * E_ + e];
}

// ---------------------------------------------------------------------------
// Wo [1024][30001] f32 -> wo_t [VP_][1024] bf16 (transposed, tiled via LDS).
// ---------------------------------------------------------------------------
__global__ __launch_bounds__(256) void transpose_wo(
    const float* __restrict__ wo, bf16_t* __restrict__ dst)
{
    __shared__ bf16_t tile[64][72];
    const int c0 = blockIdx.x * 64;
    const int k0 = blockIdx.y * 64;
    const int tx = threadIdx.x & 63, ty = threadIdx.x >> 6;

#pragma unroll
    for (int kk = ty; kk < 64; kk += 4) {
        const int col = c0 + tx;
        float v = (col < V_) ? wo[(size_t)(k0 + kk) * V_ + col] : 0.f;
        tile[kk][tx] = (bf16_t)v;
    }
    __syncthreads();
#pragma unroll
    for (int cc = ty; cc < 64; cc += 4)
        dst[(size_t)(c0 + cc) * 1024 + k0 + tx] = tile[tx][cc];
}

// ---------------------------------------------------------------------------
// Split-bf16 3-pass MFMA GEMM: C[M,N] = A[M,K]f32 @ B[K,N]f32, rel err ~2^-18
// (f32-grade; safe for loop-feeding weights — r15-proven technique).
// 128x128 tile, 4 waves (2x2), 16x16x32 MFMA, K%32==0, M/N %128==0.
// OUT=0: f32 store (ldc f32 elems); OUT=1: bf16 store (ldc bf16 elems).
// Fragment maps identical to the verified gemm_wo_mfma.
// ---------------------------------------------------------------------------
template <int OUT>
__global__ __launch_bounds__(256) void gemm_mfma_split(
    const float* __restrict__ A, int lda,
    const float* __restrict__ Bm, int ldb,
    float* __restrict__ C, int ldc, int K)
{
    __shared__ bf16_t As_h[128][40];
    __shared__ bf16_t As_l[128][40];
    __shared__ bf16_t Bs_h[128][40];
    __shared__ bf16_t Bs_l[128][40];

    const int n0  = blockIdx.x * 128;
    const int m0  = blockIdx.y * 128;
    const int tid = threadIdx.x;
    const int wave = tid >> 6, lane = tid & 63;
    const int wr = wave >> 1, wc = wave & 1;
    const int lr = lane & 15;
    const int lk = lane >> 4;

    f32x4 acc[4][4] = {};

    const int ar  = tid >> 1, ak = (tid & 1) * 16;   // A: 128 rows x 32 k
    const int bk0 = (tid >> 5) * 4, bc = (tid & 31) * 4; // B: 32 k x 128 n

    for (int k0 = 0; k0 < K; k0 += 32) {
        // stage A (16 f32/thread -> hi/lo bf16, contiguous stores)
        {
            const float* ap = &A[(size_t)(m0 + ar) * lda + k0 + ak];
            bf16x8 h0v, l0v, h1v, l1v;
#pragma unroll
            for (int q = 0; q < 2; ++q) {
                float4 v0 = *(const float4*)&ap[q * 8];
                float4 v1 = *(const float4*)&ap[q * 8 + 4];
                float xs[8] = {v0.x, v0.y, v0.z, v0.w, v1.x, v1.y, v1.z, v1.w};
#pragma unroll
                for (int e = 0; e < 8; ++e) {
                    bf16_t h = (bf16_t)xs[e];
                    if (q == 0) { h0v[e] = h; l0v[e] = (bf16_t)(xs[e] - (float)h); }
                    else        { h1v[e] = h; l1v[e] = (bf16_t)(xs[e] - (float)h); }
                }
            }
            *(bf16x8*)&As_h[ar][ak]     = h0v;
            *(bf16x8*)&As_h[ar][ak + 8] = h1v;
            *(bf16x8*)&As_l[ar][ak]     = l0v;
            *(bf16x8*)&As_l[ar][ak + 8] = l1v;
        }
        // stage B transposed (4 k-rows x 4 cols/thread, scalar stores)
        {
#pragma unroll
            for (int kk = 0; kk < 4; ++kk) {
                float4 v = *(const float4*)&Bm[(size_t)(k0 + bk0 + kk) * ldb + n0 + bc];
                float xs[4] = {v.x, v.y, v.z, v.w};
#pragma unroll
                for (int i = 0; i < 4; ++i) {
                    bf16_t h = (bf16_t)xs[i];
                    Bs_h[bc + i][bk0 + kk] = h;
                    Bs_l[bc + i][bk0 + kk] = (bf16_t)(xs[i] - (float)h);
                }
            }
        }
        __syncthreads();

        bf16x8 ah[4], alv[4], bh[4], bl[4];
#pragma unroll
        for (int m = 0; m < 4; ++m) {
            ah[m]  = *(const bf16x8*)&As_h[wr * 64 + m * 16 + lr][lk * 8];
            alv[m] = *(const bf16x8*)&As_l[wr * 64 + m * 16 + lr][lk * 8];
        }
#pragma unroll
        for (int n = 0; n < 4; ++n) {
            bh[n] = *(const bf16x8*)&Bs_h[wc * 64 + n * 16 + lr][lk * 8];
            bl[n] = *(const bf16x8*)&Bs_l[wc * 64 + n * 16 + lr][lk * 8];
        }
#pragma unroll
        for (int m = 0; m < 4; ++m)
#pragma unroll
            for (int n = 0; n < 4; ++n) {
                acc[m][n] = __builtin_amdgcn_mfma_f32_16x16x32_bf16(ah[m],  bh[n], acc[m][n], 0, 0, 0);
                acc[m][n] = __builtin_amdgcn_mfma_f32_16x16x32_bf16(ah[m],  bl[n], acc[m][n], 0, 0, 0);
                acc[m][n] = __builtin_amdgcn_mfma_f32_16x16x32_bf16(alv[m], bh[n], acc[m][n], 0, 0, 0);
            }
        __syncthreads();
    }

#pragma unroll
    for (int m = 0; m < 4; ++m) {
        const int row = m0 + wr * 64 + m * 16 + lk * 4;
#pragma unroll
        for (int n = 0; n < 4; ++n) {
            const int col = n0 + wc * 64 + n * 16 + lr;
#pragma unroll
            for (int r = 0; r < 4; ++r) {
                if (OUT == 0)
                    C[(size_t)(row + r) * ldc + col] = acc[m][n][r];
                else
                    ((bf16_t*)C)[(size_t)(row + r) * ldc + col] = (bf16_t)acc[m][n][r];
            }
        }
    }
}

// ---------------------------------------------------------------------------
// Split-K GEMM for t=0: zp[(ks*64+b)*4096+n] = sum_{k in 256-slice} h0@Uh.
// ---------------------------------------------------------------------------
__global__ __launch_bounds__(256) void zgemm_partial(
    const float* __restrict__ A, int lda,
    const float* __restrict__ Bm,
    float* __restrict__ zp)
{
    __shared__ float As[64][17];
    __shared__ float Bs[16][68];

    const int n0     = blockIdx.x * 64;
    const int ks     = blockIdx.y;
    const int k_base = ks * 256;
    const int tid    = threadIdx.x;
    const int tx     = tid & 15, ty = tid >> 4;

    float acc[4][4];
#pragma unroll
    for (int i = 0; i < 4; ++i)
#pragma unroll
        for (int j = 0; j < 4; ++j) acc[i][j] = 0.f;

    const int ra = tid >> 2, ca = (tid & 3) * 4;
    const int rb = tid >> 4, cb = (tid & 15) * 4;

    for (int kt = 0; kt < 16; ++kt) {
        const int k0 = k_base + kt * 16;
        float4 av = *(const float4*)&A[(size_t)ra * lda + k0 + ca];
        As[ra][ca + 0] = av.x;
        As[ra][ca + 1] = av.y;
        As[ra][ca + 2] = av.z;
        As[ra][ca + 3] = av.w;
        float4 bv = *(const float4*)&Bm[(size_t)(k0 + rb) * U4_ + n0 + cb];
        *(float4*)&Bs[rb][cb] = bv;
        __syncthreads();
#pragma unroll
        for (int kk = 0; kk < 16; ++kk) {
            float a_[4];
#pragma unroll
            for (int i = 0; i < 4; ++i) a_[i] = As[ty * 4 + i][kk];
            float4 bq = *(const float4*)&Bs[kk][tx * 4];
            float b_[4] = {bq.x, bq.y, bq.z, bq.w};
#pragma unroll
            for (int i = 0; i < 4; ++i)
#pragma unroll
                for (int j = 0; j < 4; ++j)
                    acc[i][j] = fmaf(a_[i], b_[j], acc[i][j]);
        }
        __syncthreads();
    }

#pragma unroll
    for (int i = 0; i < 4; ++i)
        *(float4*)&zp[((size_t)ks * 64 + ty * 4 + i) * U4_ + n0 + tx * 4] =
            make_float4(acc[i][0], acc[i][1], acc[i][2], acc[i][3]);
}

// ---------------------------------------------------------------------------
// Persistent decoder loop v10 (r15, byte-identical): phase A on MFMA via
// split-bf16, hcbuf rotation, tree'd flags, fenceless sc pipeline.
// ---------------------------------------------------------------------------
__global__ __launch_bounds__(512) void decoder_loop10(
    const float* __restrict__ zemb,   // [3200][4096] (in d_out)
    const float* __restrict__ Wcomb,  // [2048][4096]
    const float* __restrict__ keys,   // [64][50][1024]
    const float* __restrict__ memory, // [64][50][1024]
    const float* __restrict__ c0,
    float* __restrict__ hcbuf,        // [50][HCSTR_] (in d_out)
    float* __restrict__ zp,           // [4][64][4096] (sc-ops only)
    float* __restrict__ hc_all,       // [64][50][2048] (plain)
    unsigned* flags)
{
    static __shared__ __attribute__((aligned(16))) char smem[154112];
    bf16_t* wfr = (bf16_t*)smem;                    // 131072 B frag store
    float*  lA  = (float*)(smem + 131072);          // [2][2304] staging
    float*  tr  = (float*)(smem + 131072);          // [64][68] (alias)
    float*  hs  = (float*)(smem + 149504);          // 1024
    float*  sc  = (float*)(smem + 153600);          // 64
    float*  al  = (float*)(smem + 153856);          // 64

    const int beta = blockIdx.x;
    const int tid  = threadIdx.x;

    const int nt = beta & 63, ks = beta >> 6;
    const int koff = ks * 512;
    const int c0c  = nt * 64;

    // ---- pack Wcomb slice [512 k][64 cols] -> LDS fragments (once) ----
    for (int i = tid; i < 512 * 64; i += 512) {
        const int k = i >> 6, col = i & 63;
        const float w = Wcomb[(size_t)(koff + k) * U4_ + c0c + col];
        const bf16_t hi = (bf16_t)w;
        const bf16_t lo = (bf16_t)(w - (float)hi);
        const int ntile = col >> 4, lane_lo = col & 15;
        const int kk = k >> 5, kr = k & 31;
        const int lane = (kr >> 3) * 16 + lane_lo, j = kr & 7;
        const int base = ((ntile * 16 + kk) * 2) * 512 + lane * 8 + j;
        wfr[base]       = hi;
        wfr[base + 512] = lo;
    }

    const int b  = beta;
    const int u2 = tid * 2;
    float creg[2] = {0.f, 0.f};
    if (beta < 64) {
        float2 cv = *(const float2*)&c0[b * U_ + u2];
        creg[0] = cv.x;
        creg[1] = cv.y;
    }
    __syncthreads();

    // phase-A indices
    const int w    = tid >> 6, l = tid & 63;
    const int mt   = w >> 1, ntb = (w & 1) * 2;
    const int arow = mt * 16 + (l & 15);
    const int aq   = l >> 4;
    const int aphys = arow * 36 + (((aq ^ (arow & 3)) & 3) << 3);
    const int sr = tid >> 3, sc4 = (tid & 7) * 4;
    const int sq = sc4 >> 3, srem = sc4 & 7;
    const int sphys = sr * 36 + (((sq ^ (sr & 3)) & 3) << 3) + srem;

    for (int t = 0; t < T_; ++t) {
        // ---------------- phase A (t>=1): zp = hcbuf[t-1] @ Wcomb (MFMA) ----
        if (t) {
            {   // wait on producer of my k-half
                const unsigned tgt = 8u * (unsigned)t;
                const unsigned* fb = (ks < 2) ? &flags[512] : &flags[768];
                if (tid < 8) {
                    const unsigned* f = fb + tid * 32;
                    while (scload_u(f) < tgt) __builtin_amdgcn_s_sleep(1);
                }
                __syncthreads();
                cbar();
            }

            const float* apbase = &hcbuf[(size_t)(t - 1) * HCSTR_];
            {
                float4 av = *(const float4*)&apbase[(size_t)sr * 2048 + koff + sc4];
                *(float4*)&lA[sphys] = av;
            }
            __syncthreads();

            f32x4 acc[2] = {};
            for (int kk = 0; kk < 16; ++kk) {
                const int cur = kk & 1;
                float4 pre;
                if (kk < 15)
                    pre = *(const float4*)&apbase[(size_t)sr * 2048 + koff + (kk + 1) * 32 + sc4];

                const float* Ab = &lA[cur * 2304];
                float4 a0 = *(const float4*)&Ab[aphys];
                float4 a1 = *(const float4*)&Ab[aphys + 4];
                float xs[8] = {a0.x, a0.y, a0.z, a0.w, a1.x, a1.y, a1.z, a1.w};
                bf16x8 ah, alv;
#pragma unroll
                for (int e = 0; e < 8; ++e) {
                    bf16_t h = (bf16_t)xs[e];
                    ah[e]  = h;
                    alv[e] = (bf16_t)(xs[e] - (float)h);
                }
#pragma unroll
                for (int nn = 0; nn < 2; ++nn) {
                    const int fb2 = (((ntb + nn) * 16 + kk) * 2) * 512 + l * 8;
                    bf16x8 bh = *(const bf16x8*)&wfr[fb2];
                    bf16x8 bl = *(const bf16x8*)&wfr[fb2 + 512];
                    acc[nn] = __builtin_amdgcn_mfma_f32_16x16x32_bf16(ah, bh, acc[nn], 0, 0, 0);
                    acc[nn] = __builtin_amdgcn_mfma_f32_16x16x32_bf16(ah, bl, acc[nn], 0, 0, 0);
                    acc[nn] = __builtin_amdgcn_mfma_f32_16x16x32_bf16(alv, bh, acc[nn], 0, 0, 0);
                }
                if (kk < 15) {
                    *(float4*)&lA[(cur ^ 1) * 2304 + sphys] = pre;
                    __syncthreads();
                }
            }
            __syncthreads();

#pragma unroll
            for (int nn = 0; nn < 2; ++nn)
#pragma unroll
                for (int rr = 0; rr < 4; ++rr)
                    tr[(mt * 16 + (l >> 4) * 4 + rr) * 68 + (ntb + nn) * 16 + (l & 15)] =
                        acc[nn][rr];
            __syncthreads();

            {
                const int zb = tid >> 3, cg = (tid & 7) * 8;
                float4 r0 = *(const float4*)&tr[zb * 68 + cg];
                float4 r1 = *(const float4*)&tr[zb * 68 + cg + 4];
                float* zrow = &zp[((size_t)(ks * 64 + zb)) * U4_ + c0c + cg];
                scstore8(zrow + 0, r0.x, r0.y);
                scstore8(zrow + 2, r0.z, r0.w);
                scstore8(zrow + 4, r1.x, r1.y);
                scstore8(zrow + 6, r1.z, r1.w);
            }
            vm_drain();
            __syncthreads();
            if (tid == 0) scadd_u(&flags[(beta & 15) * 32]);   // zp group flag
        }

        // ---------------- phase BC: gates + attention (blocks < 64) ---------
        if (beta < 64) {
            if (t) {
                const unsigned tgt = 16u * (unsigned)t;
                if (tid < 16) {
                    const unsigned* f = &flags[tid * 32];
                    while (scload_u(f) < tgt) __builtin_amdgcn_s_sleep(1);
                }
                __syncthreads();
                cbar();
            }

            const float* ze = &zemb[((size_t)b * T_ + t) * U4_];
            float zgx[4], zgy[4];
#pragma unroll
            for (int g = 0; g < 4; ++g) {
                float2 a = *(const float2*)&ze[g * U_ + u2];
                zgx[g] = a.x;
                zgy[g] = a.y;
            }
#pragma unroll
            for (int s = 0; s < 4; ++s) {
#pragma unroll
                for (int g = 0; g < 4; ++g) {
                    float2 v = scload8(&zp[((size_t)s * 64 + b) * U4_ + g * U_ + u2]);
                    zgx[g] += v.x;
                    zgy[g] += v.y;
                }
            }

            const float six = 1.f / (1.f + expf(-zgx[0]));
            const float sfx = 1.f / (1.f + expf(-zgx[1]));
            const float tgx = tanhf(zgx[2]);
            const float sox = 1.f / (1.f + expf(-zgx[3]));
            const float cnx = sfx * creg[0] + six * tgx;
            creg[0] = cnx;
            const float hnx = sox * tanhf(cnx);

            const float siy = 1.f / (1.f + expf(-zgy[0]));
            const float sfy = 1.f / (1.f + expf(-zgy[1]));
            const float tgy = tanhf(zgy[2]);
            const float soy = 1.f / (1.f + expf(-zgy[3]));
            const float cny = sfy * creg[1] + siy * tgy;
            creg[1] = cny;
            const float hny = soy * tanhf(cny);

            float* hcb_t = &hcbuf[(size_t)t * HCSTR_];
            hs[u2]     = hnx;
            hs[u2 + 1] = hny;
            scstore8(&hcb_t[b * 2048 + u2], hnx, hny);
            *(float2*)&hc_all[((size_t)b * T_ + t) * 2048 + u2] =
                make_float2(hnx, hny);
            vm_drain();
            __syncthreads();
            if (tid == 0) scadd_u(&flags[512 + (b & 7) * 32]);  // h group flag

            const int lane = tid & 63, wv = tid >> 6;
            for (int s = wv; s < S_; s += 8) {
                const float* kp = &keys[((size_t)b * S_ + s) * U_ + lane * 16];
                const float* hp = &hs[lane * 16];
                float p = 0.f;
#pragma unroll
                for (int q = 0; q < 4; ++q) {
                    float4 kv = *(const float4*)&kp[q * 4];
                    float4 hv = *(const float4*)&hp[q * 4];
                    p = fmaf(hv.x, kv.x, p);
                    p = fmaf(hv.y, kv.y, p);
                    p = fmaf(hv.z, kv.z, p);
                    p = fmaf(hv.w, kv.w, p);
                }
#pragma unroll
                for (int off = 32; off > 0; off >>= 1)
                    p += __shfl_xor(p, off);
                if (lane == 0) sc[s] = p;
            }
            __syncthreads();

            if (tid < 64) {
                float v = (tid < S_) ? sc[tid] : -INFINITY;
                float m = v;
#pragma unroll
                for (int off = 32; off > 0; off >>= 1)
                    m = fmaxf(m, __shfl_xor(m, off));
                float e = (tid < S_) ? expf(v - m) : 0.f;
                float ssum = e;
#pragma unroll
                for (int off = 32; off > 0; off >>= 1)
                    ssum += __shfl_xor(ssum, off);
                if (tid < S_) al[tid] = e / ssum;
            }
            __syncthreads();

            {
                const float2* mp = (const float2*)&memory[(size_t)b * S_ * U_];
                float cx = 0.f, cy = 0.f;
#pragma unroll 10
                for (int s = 0; s < S_; ++s) {
                    float2 mv = mp[s * 512 + tid];
                    const float a = al[s];
                    cx = fmaf(a, mv.x, cx);
                    cy = fmaf(a, mv.y, cy);
                }
                scstore8(&hcb_t[b * 2048 + U_ + u2], cx, cy);
                *(float2*)&hc_all[((size_t)b * T_ + t) * 2048 + U_ + u2] =
                    make_float2(cx, cy);
            }
            vm_drain();
            __syncthreads();
            if (tid == 0) scadd_u(&flags[768 + (b & 7) * 32]);  // ctx group flag
        }
    }
}

// ---------------------------------------------------------------------------
// bf16 MFMA GEMM for Wo with PRE-TRANSPOSED B: C = A[3200][1024] @ Bt^T + bias
// where Bt[VP_][1024]. Both LDS stages are linear wide copies (no conflicts).
// ---------------------------------------------------------------------------
__global__ __launch_bounds__(256) void gemm_wo_mfma2(
    const bf16_t* __restrict__ A,    // [3200][1024]
    const bf16_t* __restrict__ Bt,   // [VP_][1024]
    const float*  __restrict__ bias, // [V_]
    float* __restrict__ C)           // [3200][V_]
{
    __shared__ bf16_t As[128][40];
    __shared__ bf16_t Bs[128][40];

    const int n0  = blockIdx.x * 128;
    const int m0  = blockIdx.y * 128;
    const int tid = threadIdx.x;
    const int wave = tid >> 6, lane = tid & 63;
    const int wr = wave >> 1, wc = wave & 1;
    const int lr = lane & 15;
    const int lk = lane >> 4;

    f32x4 acc[4][4] = {};

    const int ar = tid >> 1, ak = (tid & 1) * 16;   // A rows
    const int br = tid >> 1, bk = (tid & 1) * 16;   // Bt rows (cols of B)

    for (int k0 = 0; k0 < U_; k0 += 32) {
        {
            const bf16_t* ap = &A[(size_t)(m0 + ar) * U_ + k0 + ak];
            *(bf16x8*)&As[ar][ak]     = *(const bf16x8*)ap;
            *(bf16x8*)&As[ar][ak + 8] = *(const bf16x8*)(ap + 8);
        }
        {
            const bf16_t* bp = &Bt[(size_t)(n0 + br) * 1024 + k0 + bk];
            *(bf16x8*)&Bs[br][bk]     = *(const bf16x8*)bp;
            *(bf16x8*)&Bs[br][bk + 8] = *(const bf16x8*)(bp + 8);
        }
        __syncthreads();

        bf16x8 af[4], bf[4];
#pragma unroll
        for (int m = 0; m < 4; ++m)
            af[m] = *(const bf16x8*)&As[wr * 64 + m * 16 + lr][lk * 8];
#pragma unroll
        for (int n = 0; n < 4; ++n)
            bf[n] = *(const bf16x8*)&Bs[wc * 64 + n * 16 + lr][lk * 8];
#pragma unroll
        for (int m = 0; m < 4; ++m)
#pragma unroll
            for (int n = 0; n < 4; ++n)
                acc[m][n] = __builtin_amdgcn_mfma_f32_16x16x32_bf16(
                    af[m], bf[n], acc[m][n], 0, 0, 0);
        __syncthreads();
    }

#pragma unroll
    for (int m = 0; m < 4; ++m) {
        const int row = m0 + wr * 64 + m * 16 + lk * 4;
#pragma unroll
        for (int n = 0; n < 4; ++n) {
            const int col = n0 + wc * 64 + n * 16 + lr;
            if (col < V_) {
                const float bb = bias[col];
#pragma unroll
                for (int r = 0; r < 4; ++r)
                    C[(size_t)(row + r) * V_ + col] = acc[m][n][r] + bb;
            }
        }
    }
}

// ---------------------------------------------------------------------------
extern "C" void kernel_launch(void* const* d_in, const int* in_sizes, int n_in,
                              void* d_out, int out_size, void* d_ws, size_t ws_size,
                              hipStream_t stream)
{
    const int*   tokens = (const int*)  d_in[0];
    const float* memory = (const float*)d_in[1];
    const float* h0     = (const float*)d_in[2];
    const float* c0     = (const float*)d_in[3];
    const float* emb    = (const float*)d_in[4];
    const float* Wx     = (const float*)d_in[5];
    const float* Uh     = (const float*)d_in[6];
    const float* bvec   = (const float*)d_in[7];
    const float* Wm     = (const float*)d_in[8];
    const float* Wa     = (const float*)d_in[9];
    const float* Wo     = (const float*)d_in[10];
    const float* bo     = (const float*)d_in[11];
    float* out = (float*)d_out;

    // ---- workspace layout (float units) ----
    float* ws = (float*)d_ws;
    size_t off = 0;
    float*   Wcomb  = ws + off; off += (size_t)2048 * U4_;      // 33.55 MB
    float*   keys   = ws + off; off += (size_t)B_ * S_ * U_;    // 13.11 MB
    float*   hc_all = ws + off; off += (size_t)B_ * T_ * 2048;  // 26.21 MB
    float*   zp     = ws + off; off += (size_t)4 * B_ * U4_;    //  4.19 MB
    float*   x_emb  = ws + off; off += (size_t)B_ * T_ * E_;    //  1.28 MB
    unsigned* flags = (unsigned*)(ws + off); off += 1024;       //  4 KB
    bf16_t*  wo_t   = (bf16_t*)(ws + off); off += (size_t)VP_ * 1024 / 2; // 61.6 MB

    // d_out-resident scratch (all dead before the final GEMM writes out):
    float* zemb  = out;                           // [3200][4096]   52.4 MB
    float* hcbuf = out + (size_t)3200 * U4_;      // [50][HCSTR_]   26.2 MB
    bf16_t* abf  = (bf16_t*)Wcomb;                // post-loop alias (Wcomb dead)

    (void)ws_size;
    (void)hipMemsetAsync(flags, 0, 1024 * sizeof(unsigned), stream);

    // ---- pre-loop ----
    gather_emb<<<B_ * T_, 128, 0, stream>>>(tokens, emb, x_emb);
    // zemb = x_emb @ Wx[0:100] + b  (f32; K=100 tail)
    gemm128<<<dim3(32, 25), 256, 0, stream>>>(
        x_emb, E_, Wx, U4_, zemb, U4_, U4_, E_, bvec);
    // Wcomb = Wa @ Wx[100:1124]  (split-MFMA, f32-grade)
    gemm_mfma_split<0><<<dim3(32, 16), 256, 0, stream>>>(
        Wa, U_, Wx + (size_t)E_ * U4_, U4_, Wcomb, U4_, U_);
    add_inplace<<<(1024 * U4_) / 256, 256, 0, stream>>>(Wcomb, Uh, 1024 * U4_);
    // keys = memory @ Wm  (split-MFMA, f32-grade)
    gemm_mfma_split<0><<<dim3(8, 25), 256, 0, stream>>>(
        memory, U_, Wm, U_, keys, U_, U_);
    // t=0 z-partials
    zgemm_partial<<<dim3(64, 4), 256, 0, stream>>>(h0, U_, Uh, zp);
    // Wo -> transposed bf16
    transpose_wo<<<dim3(VP_ / 64, 1024 / 64), 256, 0, stream>>>(Wo, wo_t);

    // ---- persistent recurrent loop (phase A on MFMA) ----
    decoder_loop10<<<256, 512, 0, stream>>>(
        zemb, Wcomb, keys, memory, c0, hcbuf, zp, hc_all, flags);

    // ---- post-loop ----
    // abf = bf16(hc_all @ Wa)   (split-MFMA, direct bf16 out; Wcomb dead)
    gemm_mfma_split<1><<<dim3(8, 25), 256, 0, stream>>>(
        hc_all, 2048, Wa, U_, (float*)abf, U_, 2048);
    // out = abf @ wo_t^T + bo
    gemm_wo_mfma2<<<dim3(VP_ / 128, 25), 256, 0, stream>>>(abf, wo_t, bo, out);
}

// Round 17
// 2135.465 us; speedup vs baseline: 3.2376x; 1.0361x over previous
//
#include <hip/hip_runtime.h>
#include <math.h>

#define B_  64
#define T_  50
#define S_  50
#define U_  1024
#define E_  100
#define V_  30001
#define U4_ 4096
#define VP_ 30080       // V padded to a multiple of 128 for bf16 staging
#define HCSTR_ 131136   // hcbuf plane stride: 64*2048 + 64 pad floats

typedef __bf16 bf16_t;
typedef bf16_t bf16x8 __attribute__((ext_vector_type(8)));
typedef float  f32x4  __attribute__((ext_vector_type(4)));
typedef unsigned long long u64_t;

// ---------------------------------------------------------------------------
// Coherence-point accessors (SYSTEM scope -> sc0+sc1; proven r11-r16).
// ---------------------------------------------------------------------------
__device__ __forceinline__ float2 scload8(const float* p) {
    u64_t v = __hip_atomic_load((const u64_t*)p, __ATOMIC_RELAXED,
                                __HIP_MEMORY_SCOPE_SYSTEM);
    union { u64_t u; float2 f; } c; c.u = v; return c.f;
}
__device__ __forceinline__ void scstore8(float* p, float x, float y) {
    union { u64_t u; float2 f; } c; c.f = make_float2(x, y);
    __hip_atomic_store((u64_t*)p, c.u, __ATOMIC_RELAXED,
                       __HIP_MEMORY_SCOPE_SYSTEM);
}
__device__ __forceinline__ unsigned scload_u(const unsigned* p) {
    return __hip_atomic_load(p, __ATOMIC_RELAXED, __HIP_MEMORY_SCOPE_SYSTEM);
}
__device__ __forceinline__ void scadd_u(unsigned* p) {
    __hip_atomic_fetch_add(p, 1u, __ATOMIC_RELAXED, __HIP_MEMORY_SCOPE_SYSTEM);
}
__device__ __forceinline__ void vm_drain() {
    asm volatile("s_waitcnt vmcnt(0)" ::: "memory");
}
__device__ __forceinline__ void cbar() { asm volatile("" ::: "memory"); }

__global__ void add_inplace(float* __restrict__ dst, const float* __restrict__ src, int n)
{
    int i = blockIdx.x * blockDim.x + threadIdx.x;
    if (i < n) dst[i] += src[i];
}

// x_emb padded to K=128: cols 0..99 = emb[token], col 100 = 1.0 (bias row
// selector), cols 101..127 = 0.
__global__ void gather_emb_pad(const int* __restrict__ tokens,
                               const float* __restrict__ emb,
                               float* __restrict__ xe)
{
    const int r = blockIdx.x;
    const int e = threadIdx.x;
    float v;
    if (e < E_)       v = emb[(size_t)tokens[r] * E_ + e];
    else if (e == E_) v = 1.f;
    else              v = 0.f;
    xe[(size_t)r * 128 + e] = v;
}

// wx_pad[128][4096]: rows 0..99 = Wx top, row 100 = bvec, rows 101..127 = 0.
__global__ void pad_wx(const float* __restrict__ Wx,
                       const float* __restrict__ bvec,
                       float* __restrict__ dst)
{
    const int col = blockIdx.x * 256 + threadIdx.x;
    const int row = blockIdx.y;
    float v;
    if (row < E_)       v = Wx[(size_t)row * U4_ + col];
    else if (row == E_) v = bvec[col];
    else                v = 0.f;
    dst[(size_t)row * U4_ + col] = v;
}

// ---------------------------------------------------------------------------
// Wo [1024][30001] f32 -> wo_t [VP_][1024] bf16 (transposed, tiled via LDS).
// ---------------------------------------------------------------------------
__global__ __launch_bounds__(256) void transpose_wo(
    const float* __restrict__ wo, bf16_t* __restrict__ dst)
{
    __shared__ bf16_t tile[64][72];
    const int c0 = blockIdx.x * 64;
    const int k0 = blockIdx.y * 64;
    const int tx = threadIdx.x & 63, ty = threadIdx.x >> 6;

#pragma unroll
    for (int kk = ty; kk < 64; kk += 4) {
        const int col = c0 + tx;
        float v = (col < V_) ? wo[(size_t)(k0 + kk) * V_ + col] : 0.f;
        tile[kk][tx] = (bf16_t)v;
    }
    __syncthreads();
#pragma unroll
    for (int cc = ty; cc < 64; cc += 4)
        dst[(size_t)(c0 + cc) * 1024 + k0 + tx] = tile[tx][cc];
}

// ---------------------------------------------------------------------------
// Split-bf16 3-pass MFMA GEMM (r15-proven): C = A@B, rel err ~2^-18.
// 128x128 tile, 4 waves, 16x16x32. OUT=0 f32 store; OUT=1 bf16 store.
// ---------------------------------------------------------------------------
template <int OUT>
__global__ __launch_bounds__(256) void gemm_mfma_split(
    const float* __restrict__ A, int lda,
    const float* __restrict__ Bm, int ldb,
    float* __restrict__ C, int ldc, int K)
{
    __shared__ bf16_t As_h[128][40];
    __shared__ bf16_t As_l[128][40];
    __shared__ bf16_t Bs_h[128][40];
    __shared__ bf16_t Bs_l[128][40];

    const int n0  = blockIdx.x * 128;
    const int m0  = blockIdx.y * 128;
    const int tid = threadIdx.x;
    const int wave = tid >> 6, lane = tid & 63;
    const int wr = wave >> 1, wc = wave & 1;
    const int lr = lane & 15;
    const int lk = lane >> 4;

    f32x4 acc[4][4] = {};

    const int ar  = tid >> 1, ak = (tid & 1) * 16;
    const int bk0 = (tid >> 5) * 4, bc = (tid & 31) * 4;

    for (int k0 = 0; k0 < K; k0 += 32) {
        {
            const float* ap = &A[(size_t)(m0 + ar) * lda + k0 + ak];
            bf16x8 h0v, l0v, h1v, l1v;
#pragma unroll
            for (int q = 0; q < 2; ++q) {
                float4 v0 = *(const float4*)&ap[q * 8];
                float4 v1 = *(const float4*)&ap[q * 8 + 4];
                float xs[8] = {v0.x, v0.y, v0.z, v0.w, v1.x, v1.y, v1.z, v1.w};
#pragma unroll
                for (int e = 0; e < 8; ++e) {
                    bf16_t h = (bf16_t)xs[e];
                    if (q == 0) { h0v[e] = h; l0v[e] = (bf16_t)(xs[e] - (float)h); }
                    else        { h1v[e] = h; l1v[e] = (bf16_t)(xs[e] - (float)h); }
                }
            }
            *(bf16x8*)&As_h[ar][ak]     = h0v;
            *(bf16x8*)&As_h[ar][ak + 8] = h1v;
            *(bf16x8*)&As_l[ar][ak]     = l0v;
            *(bf16x8*)&As_l[ar][ak + 8] = l1v;
        }
        {
#pragma unroll
            for (int kk = 0; kk < 4; ++kk) {
                float4 v = *(const float4*)&Bm[(size_t)(k0 + bk0 + kk) * ldb + n0 + bc];
                float xs[4] = {v.x, v.y, v.z, v.w};
#pragma unroll
                for (int i = 0; i < 4; ++i) {
                    bf16_t h = (bf16_t)xs[i];
                    Bs_h[bc + i][bk0 + kk] = h;
                    Bs_l[bc + i][bk0 + kk] = (bf16_t)(xs[i] - (float)h);
                }
            }
        }
        __syncthreads();

        bf16x8 ah[4], alv[4], bh[4], bl[4];
#pragma unroll
        for (int m = 0; m < 4; ++m) {
            ah[m]  = *(const bf16x8*)&As_h[wr * 64 + m * 16 + lr][lk * 8];
            alv[m] = *(const bf16x8*)&As_l[wr * 64 + m * 16 + lr][lk * 8];
        }
#pragma unroll
        for (int n = 0; n < 4; ++n) {
            bh[n] = *(const bf16x8*)&Bs_h[wc * 64 + n * 16 + lr][lk * 8];
            bl[n] = *(const bf16x8*)&Bs_l[wc * 64 + n * 16 + lr][lk * 8];
        }
#pragma unroll
        for (int m = 0; m < 4; ++m)
#pragma unroll
            for (int n = 0; n < 4; ++n) {
                acc[m][n] = __builtin_amdgcn_mfma_f32_16x16x32_bf16(ah[m],  bh[n], acc[m][n], 0, 0, 0);
                acc[m][n] = __builtin_amdgcn_mfma_f32_16x16x32_bf16(ah[m],  bl[n], acc[m][n], 0, 0, 0);
                acc[m][n] = __builtin_amdgcn_mfma_f32_16x16x32_bf16(alv[m], bh[n], acc[m][n], 0, 0, 0);
            }
        __syncthreads();
    }

#pragma unroll
    for (int m = 0; m < 4; ++m) {
        const int row = m0 + wr * 64 + m * 16 + lk * 4;
#pragma unroll
        for (int n = 0; n < 4; ++n) {
            const int col = n0 + wc * 64 + n * 16 + lr;
#pragma unroll
            for (int r = 0; r < 4; ++r) {
                if (OUT == 0)
                    C[(size_t)(row + r) * ldc + col] = acc[m][n][r];
                else
                    ((bf16_t*)C)[(size_t)(row + r) * ldc + col] = (bf16_t)acc[m][n][r];
            }
        }
    }
}

// ---------------------------------------------------------------------------
// Split-K GEMM for t=0: zp[(ks*64+b)*4096+n] = sum_{k in 256-slice} h0@Uh.
// ---------------------------------------------------------------------------
__global__ __launch_bounds__(256) void zgemm_partial(
    const float* __restrict__ A, int lda,
    const float* __restrict__ Bm,
    float* __restrict__ zp)
{
    __shared__ float As[64][17];
    __shared__ float Bs[16][68];

    const int n0     = blockIdx.x * 64;
    const int ks     = blockIdx.y;
    const int k_base = ks * 256;
    const int tid    = threadIdx.x;
    const int tx     = tid & 15, ty = tid >> 4;

    float acc[4][4];
#pragma unroll
    for (int i = 0; i < 4; ++i)
#pragma unroll
        for (int j = 0; j < 4; ++j) acc[i][j] = 0.f;

    const int ra = tid >> 2, ca = (tid & 3) * 4;
    const int rb = tid >> 4, cb = (tid & 15) * 4;

    for (int kt = 0; kt < 16; ++kt) {
        const int k0 = k_base + kt * 16;
        float4 av = *(const float4*)&A[(size_t)ra * lda + k0 + ca];
        As[ra][ca + 0] = av.x;
        As[ra][ca + 1] = av.y;
        As[ra][ca + 2] = av.z;
        As[ra][ca + 3] = av.w;
        float4 bv = *(const float4*)&Bm[(size_t)(k0 + rb) * U4_ + n0 + cb];
        *(float4*)&Bs[rb][cb] = bv;
        __syncthreads();
#pragma unroll
        for (int kk = 0; kk < 16; ++kk) {
            float a_[4];
#pragma unroll
            for (int i = 0; i < 4; ++i) a_[i] = As[ty * 4 + i][kk];
            float4 bq = *(const float4*)&Bs[kk][tx * 4];
            float b_[4] = {bq.x, bq.y, bq.z, bq.w};
#pragma unroll
            for (int i = 0; i < 4; ++i)
#pragma unroll
                for (int j = 0; j < 4; ++j)
                    acc[i][j] = fmaf(a_[i], b_[j], acc[i][j]);
        }
        __syncthreads();
    }

#pragma unroll
    for (int i = 0; i < 4; ++i)
        *(float4*)&zp[((size_t)ks * 64 + ty * 4 + i) * U4_ + n0 + tx * 4] =
            make_float4(acc[i][0], acc[i][1], acc[i][2], acc[i][3]);
}

// ---------------------------------------------------------------------------
// Persistent decoder loop v11 = r15/r16 with phase A's A-fragments read
// DIRECTLY from global (per-lane 32B loads of the L2-hot fresh hcbuf plane),
// eliminating the lA LDS staging and all 32 per-step staging syncthreads.
// Everything else (flags, hcbuf rotation, BC, sc pipeline) unchanged.
// LDS: wfr 131072 + tr 17408 + hs 4096 + sc 256 + al 256 = 153088 B.
// ---------------------------------------------------------------------------
__global__ __launch_bounds__(512) void decoder_loop11(
    const float* __restrict__ zemb,   // [3200][4096] (in d_out)
    const float* __restrict__ Wcomb,  // [2048][4096]
    const float* __restrict__ keys,   // [64][50][1024]
    const float* __restrict__ memory, // [64][50][1024]
    const float* __restrict__ c0,
    float* __restrict__ hcbuf,        // [50][HCSTR_] (in d_out)
    float* __restrict__ zp,           // [4][64][4096] (sc-ops only)
    float* __restrict__ hc_all,       // [64][50][2048] (plain)
    unsigned* flags)
{
    static __shared__ __attribute__((aligned(16))) char smem[153088];
    bf16_t* wfr = (bf16_t*)smem;                    // 131072 B frag store
    float*  tr  = (float*)(smem + 131072);          // [64][68] transpose
    float*  hs  = (float*)(smem + 148480);          // 1024
    float*  sc  = (float*)(smem + 152576);          // 64
    float*  al  = (float*)(smem + 152832);          // 64

    const int beta = blockIdx.x;
    const int tid  = threadIdx.x;

    const int nt = beta & 63, ks = beta >> 6;
    const int koff = ks * 512;
    const int c0c  = nt * 64;

    // ---- pack Wcomb slice [512 k][64 cols] -> LDS fragments (once) ----
    for (int i = tid; i < 512 * 64; i += 512) {
        const int k = i >> 6, col = i & 63;
        const float w = Wcomb[(size_t)(koff + k) * U4_ + c0c + col];
        const bf16_t hi = (bf16_t)w;
        const bf16_t lo = (bf16_t)(w - (float)hi);
        const int ntile = col >> 4, lane_lo = col & 15;
        const int kk = k >> 5, kr = k & 31;
        const int lane = (kr >> 3) * 16 + lane_lo, j = kr & 7;
        const int base = ((ntile * 16 + kk) * 2) * 512 + lane * 8 + j;
        wfr[base]       = hi;
        wfr[base + 512] = lo;
    }

    const int b  = beta;
    const int u2 = tid * 2;
    float creg[2] = {0.f, 0.f};
    if (beta < 64) {
        float2 cv = *(const float2*)&c0[b * U_ + u2];
        creg[0] = cv.x;
        creg[1] = cv.y;
    }
    __syncthreads();

    // phase-A indices (8 waves; wave covers rows mt*16..+16, n-tiles ntb,ntb+1)
    const int w  = tid >> 6, l = tid & 63;
    const int mt = w >> 1, ntb = (w & 1) * 2;
    const int arow = mt * 16 + (l & 15);
    const int aq   = l >> 4;
    // per-thread constant base into the A plane (offset by kk*32 floats)
    const size_t abase = (size_t)arow * 2048 + koff + aq * 8;

    for (int t = 0; t < T_; ++t) {
        // ---------------- phase A (t>=1): zp = hcbuf[t-1] @ Wcomb (MFMA) ----
        if (t) {
            {   // wait on producer of my k-half
                const unsigned tgt = 8u * (unsigned)t;
                const unsigned* fb = (ks < 2) ? &flags[512] : &flags[768];
                if (tid < 8) {
                    const unsigned* f = fb + tid * 32;
                    while (scload_u(f) < tgt) __builtin_amdgcn_s_sleep(1);
                }
                __syncthreads();
                cbar();
            }

            const float* ap = &hcbuf[(size_t)(t - 1) * HCSTR_ + abase];

            f32x4 acc[2] = {};
            // pipelined direct-from-global A fragments (no LDS staging)
            float4 ca0 = *(const float4*)&ap[0];
            float4 ca1 = *(const float4*)&ap[4];
#pragma unroll
            for (int kk = 0; kk < 16; ++kk) {
                float4 pa0, pa1;
                if (kk < 15) {
                    pa0 = *(const float4*)&ap[(kk + 1) * 32];
                    pa1 = *(const float4*)&ap[(kk + 1) * 32 + 4];
                }
                float xs[8] = {ca0.x, ca0.y, ca0.z, ca0.w,
                               ca1.x, ca1.y, ca1.z, ca1.w};
                bf16x8 ah, alv;
#pragma unroll
                for (int e = 0; e < 8; ++e) {
                    bf16_t h = (bf16_t)xs[e];
                    ah[e]  = h;
                    alv[e] = (bf16_t)(xs[e] - (float)h);
                }
#pragma unroll
                for (int nn = 0; nn < 2; ++nn) {
                    const int fb2 = (((ntb + nn) * 16 + kk) * 2) * 512 + l * 8;
                    bf16x8 bh = *(const bf16x8*)&wfr[fb2];
                    bf16x8 bl = *(const bf16x8*)&wfr[fb2 + 512];
                    acc[nn] = __builtin_amdgcn_mfma_f32_16x16x32_bf16(ah, bh, acc[nn], 0, 0, 0);
                    acc[nn] = __builtin_amdgcn_mfma_f32_16x16x32_bf16(ah, bl, acc[nn], 0, 0, 0);
                    acc[nn] = __builtin_amdgcn_mfma_f32_16x16x32_bf16(alv, bh, acc[nn], 0, 0, 0);
                }
                ca0 = pa0;
                ca1 = pa1;
            }

            // acc -> LDS transpose (C/D map: col=l&15, row=(l>>4)*4+reg)
#pragma unroll
            for (int nn = 0; nn < 2; ++nn)
#pragma unroll
                for (int rr = 0; rr < 4; ++rr)
                    tr[(mt * 16 + (l >> 4) * 4 + rr) * 68 + (ntb + nn) * 16 + (l & 15)] =
                        acc[nn][rr];
            __syncthreads();

            // vectorized sc-stores of zp
            {
                const int zb = tid >> 3, cg = (tid & 7) * 8;
                float4 r0 = *(const float4*)&tr[zb * 68 + cg];
                float4 r1 = *(const float4*)&tr[zb * 68 + cg + 4];
                float* zrow = &zp[((size_t)(ks * 64 + zb)) * U4_ + c0c + cg];
                scstore8(zrow + 0, r0.x, r0.y);
                scstore8(zrow + 2, r0.z, r0.w);
                scstore8(zrow + 4, r1.x, r1.y);
                scstore8(zrow + 6, r1.z, r1.w);
            }
            vm_drain();
            __syncthreads();
            if (tid == 0) scadd_u(&flags[(beta & 15) * 32]);   // zp group flag
        }

        // ---------------- phase BC: gates + attention (blocks < 64) ---------
        if (beta < 64) {
            if (t) {
                const unsigned tgt = 16u * (unsigned)t;
                if (tid < 16) {
                    const unsigned* f = &flags[tid * 32];
                    while (scload_u(f) < tgt) __builtin_amdgcn_s_sleep(1);
                }
                __syncthreads();
                cbar();
            }

            const float* ze = &zemb[((size_t)b * T_ + t) * U4_];
            float zgx[4], zgy[4];
#pragma unroll
            for (int g = 0; g < 4; ++g) {
                float2 a = *(const float2*)&ze[g * U_ + u2];
                zgx[g] = a.x;
                zgy[g] = a.y;
            }
#pragma unroll
            for (int s = 0; s < 4; ++s) {
#pragma unroll
                for (int g = 0; g < 4; ++g) {
                    float2 v = scload8(&zp[((size_t)s * 64 + b) * U4_ + g * U_ + u2]);
                    zgx[g] += v.x;
                    zgy[g] += v.y;
                }
            }

            const float six = 1.f / (1.f + expf(-zgx[0]));
            const float sfx = 1.f / (1.f + expf(-zgx[1]));
            const float tgx = tanhf(zgx[2]);
            const float sox = 1.f / (1.f + expf(-zgx[3]));
            const float cnx = sfx * creg[0] + six * tgx;
            creg[0] = cnx;
            const float hnx = sox * tanhf(cnx);

            const float siy = 1.f / (1.f + expf(-zgy[0]));
            const float sfy = 1.f / (1.f + expf(-zgy[1]));
            const float tgy = tanhf(zgy[2]);
            const float soy = 1.f / (1.f + expf(-zgy[3]));
            const float cny = sfy * creg[1] + siy * tgy;
            creg[1] = cny;
            const float hny = soy * tanhf(cny);

            float* hcb_t = &hcbuf[(size_t)t * HCSTR_];
            hs[u2]     = hnx;
            hs[u2 + 1] = hny;
            scstore8(&hcb_t[b * 2048 + u2], hnx, hny);
            *(float2*)&hc_all[((size_t)b * T_ + t) * 2048 + u2] =
                make_float2(hnx, hny);
            vm_drain();
            __syncthreads();
            if (tid == 0) scadd_u(&flags[512 + (b & 7) * 32]);  // h group flag

            const int lane = tid & 63, wv = tid >> 6;
            for (int s = wv; s < S_; s += 8) {
                const float* kp = &keys[((size_t)b * S_ + s) * U_ + lane * 16];
                const float* hp = &hs[lane * 16];
                float p = 0.f;
#pragma unroll
                for (int q = 0; q < 4; ++q) {
                    float4 kv = *(const float4*)&kp[q * 4];
                    float4 hv = *(const float4*)&hp[q * 4];
                    p = fmaf(hv.x, kv.x, p);
                    p = fmaf(hv.y, kv.y, p);
                    p = fmaf(hv.z, kv.z, p);
                    p = fmaf(hv.w, kv.w, p);
                }
#pragma unroll
                for (int off = 32; off > 0; off >>= 1)
                    p += __shfl_xor(p, off);
                if (lane == 0) sc[s] = p;
            }
            __syncthreads();

            if (tid < 64) {
                float v = (tid < S_) ? sc[tid] : -INFINITY;
                float m = v;
#pragma unroll
                for (int off = 32; off > 0; off >>= 1)
                    m = fmaxf(m, __shfl_xor(m, off));
                float e = (tid < S_) ? expf(v - m) : 0.f;
                float ssum = e;
#pragma unroll
                for (int off = 32; off > 0; off >>= 1)
                    ssum += __shfl_xor(ssum, off);
                if (tid < S_) al[tid] = e / ssum;
            }
            __syncthreads();

            {
                const float2* mp = (const float2*)&memory[(size_t)b * S_ * U_];
                float cx = 0.f, cy = 0.f;
#pragma unroll 10
                for (int s = 0; s < S_; ++s) {
                    float2 mv = mp[s * 512 + tid];
                    const float a = al[s];
                    cx = fmaf(a, mv.x, cx);
                    cy = fmaf(a, mv.y, cy);
                }
                scstore8(&hcb_t[b * 2048 + U_ + u2], cx, cy);
                *(float2*)&hc_all[((size_t)b * T_ + t) * 2048 + U_ + u2] =
                    make_float2(cx, cy);
            }
            vm_drain();
            __syncthreads();
            if (tid == 0) scadd_u(&flags[768 + (b & 7) * 32]);  // ctx group flag
        }
    }
}

// ---------------------------------------------------------------------------
// bf16 MFMA GEMM for Wo, DOUBLE-BUFFERED: C = A[3200][1024] @ Bt^T + bias,
// Bt[VP_][1024]. Prefetch next k-chunk into regs during MFMA; 1 sync/iter.
// ---------------------------------------------------------------------------
__global__ __launch_bounds__(256) void gemm_wo_mfma3(
    const bf16_t* __restrict__ A,    // [3200][1024]
    const bf16_t* __restrict__ Bt,   // [VP_][1024]
    const float*  __restrict__ bias, // [V_]
    float* __restrict__ C)           // [3200][V_]
{
    __shared__ bf16_t As[2][128][40];
    __shared__ bf16_t Bs[2][128][40];

    const int n0  = blockIdx.x * 128;
    const int m0  = blockIdx.y * 128;
    const int tid = threadIdx.x;
    const int wave = tid >> 6, lane = tid & 63;
    const int wr = wave >> 1, wc = wave & 1;
    const int lr = lane & 15;
    const int lk = lane >> 4;

    f32x4 acc[4][4] = {};

    const int ar = tid >> 1, ak = (tid & 1) * 16;
    const bf16_t* apb = &A[(size_t)(m0 + ar) * U_ + ak];
    const bf16_t* bpb = &Bt[(size_t)(n0 + ar) * U_ + ak];

    // prologue: stage k0=0 into buffer 0
    {
        *(bf16x8*)&As[0][ar][ak]     = *(const bf16x8*)&apb[0];
        *(bf16x8*)&As[0][ar][ak + 8] = *(const bf16x8*)&apb[8];
        *(bf16x8*)&Bs[0][ar][ak]     = *(const bf16x8*)&bpb[0];
        *(bf16x8*)&Bs[0][ar][ak + 8] = *(const bf16x8*)&bpb[8];
    }
    __syncthreads();

    for (int k0 = 0; k0 < U_; k0 += 32) {
        const int cur = (k0 >> 5) & 1;
        bf16x8 na0, na1, nb0, nb1;
        const bool more = (k0 + 32 < U_);
        if (more) {
            na0 = *(const bf16x8*)&apb[k0 + 32];
            na1 = *(const bf16x8*)&apb[k0 + 40];
            nb0 = *(const bf16x8*)&bpb[k0 + 32];
            nb1 = *(const bf16x8*)&bpb[k0 + 40];
        }

        bf16x8 af[4], bf[4];
#pragma unroll
        for (int m = 0; m < 4; ++m)
            af[m] = *(const bf16x8*)&As[cur][wr * 64 + m * 16 + lr][lk * 8];
#pragma unroll
        for (int n = 0; n < 4; ++n)
            bf[n] = *(const bf16x8*)&Bs[cur][wc * 64 + n * 16 + lr][lk * 8];
#pragma unroll
        for (int m = 0; m < 4; ++m)
#pragma unroll
            for (int n = 0; n < 4; ++n)
                acc[m][n] = __builtin_amdgcn_mfma_f32_16x16x32_bf16(
                    af[m], bf[n], acc[m][n], 0, 0, 0);

        if (more) {
            *(bf16x8*)&As[cur ^ 1][ar][ak]     = na0;
            *(bf16x8*)&As[cur ^ 1][ar][ak + 8] = na1;
            *(bf16x8*)&Bs[cur ^ 1][ar][ak]     = nb0;
            *(bf16x8*)&Bs[cur ^ 1][ar][ak + 8] = nb1;
        }
        __syncthreads();
    }

#pragma unroll
    for (int m = 0; m < 4; ++m) {
        const int row = m0 + wr * 64 + m * 16 + lk * 4;
#pragma unroll
        for (int n = 0; n < 4; ++n) {
            const int col = n0 + wc * 64 + n * 16 + lr;
            if (col < V_) {
                const float bb = bias[col];
#pragma unroll
                for (int r = 0; r < 4; ++r)
                    C[(size_t)(row + r) * V_ + col] = acc[m][n][r] + bb;
            }
        }
    }
}

// ---------------------------------------------------------------------------
extern "C" void kernel_launch(void* const* d_in, const int* in_sizes, int n_in,
                              void* d_out, int out_size, void* d_ws, size_t ws_size,
                              hipStream_t stream)
{
    const int*   tokens = (const int*)  d_in[0];
    const float* memory = (const float*)d_in[1];
    const float* h0     = (const float*)d_in[2];
    const float* c0     = (const float*)d_in[3];
    const float* emb    = (const float*)d_in[4];
    const float* Wx     = (const float*)d_in[5];
    const float* Uh     = (const float*)d_in[6];
    const float* bvec   = (const float*)d_in[7];
    const float* Wm     = (const float*)d_in[8];
    const float* Wa     = (const float*)d_in[9];
    const float* Wo     = (const float*)d_in[10];
    const float* bo     = (const float*)d_in[11];
    float* out = (float*)d_out;

    // ---- workspace layout (float units) ----
    float* ws = (float*)d_ws;
    size_t off = 0;
    float*   Wcomb  = ws + off; off += (size_t)2048 * U4_;      // 33.55 MB
    float*   keys   = ws + off; off += (size_t)B_ * S_ * U_;    // 13.11 MB
    float*   hc_all = ws + off; off += (size_t)B_ * T_ * 2048;  // 26.21 MB
    float*   zp     = ws + off; off += (size_t)4 * B_ * U4_;    //  4.19 MB
    float*   x_emb  = ws + off; off += (size_t)B_ * T_ * 128;   //  1.64 MB
    unsigned* flags = (unsigned*)(ws + off); off += 1024;       //  4 KB
    bf16_t*  wo_t   = (bf16_t*)(ws + off); off += (size_t)VP_ * 1024 / 2; // 61.6 MB

    // d_out-resident scratch (all dead before the final GEMM writes out):
    float* zemb   = out;                               // [3200][4096]  52.4 MB
    float* hcbuf  = out + (size_t)3200 * U4_;          // [50][HCSTR_]  26.2 MB
    float* wx_pad = out + (size_t)3200 * U4_ + (size_t)T_ * HCSTR_; // [128][4096] 2.1 MB
    bf16_t* abf   = (bf16_t*)Wcomb;                    // post-loop alias

    (void)ws_size;
    (void)hipMemsetAsync(flags, 0, 1024 * sizeof(unsigned), stream);

    // ---- pre-loop ----
    gather_emb_pad<<<B_ * T_, 128, 0, stream>>>(tokens, emb, x_emb);
    pad_wx<<<dim3(U4_ / 256, 128), 256, 0, stream>>>(Wx, bvec, wx_pad);
    // zemb = x_emb_pad @ wx_pad  (split-MFMA; bias folded via 1.0 row)
    gemm_mfma_split<0><<<dim3(32, 25), 256, 0, stream>>>(
        x_emb, 128, wx_pad, U4_, zemb, U4_, 128);
    // Wcomb = Wa @ Wx[100:1124]  (split-MFMA, f32-grade)
    gemm_mfma_split<0><<<dim3(32, 16), 256, 0, stream>>>(
        Wa, U_, Wx + (size_t)E_ * U4_, U4_, Wcomb, U4_, U_);
    add_inplace<<<(1024 * U4_) / 256, 256, 0, stream>>>(Wcomb, Uh, 1024 * U4_);
    // keys = memory @ Wm  (split-MFMA, f32-grade)
    gemm_mfma_split<0><<<dim3(8, 25), 256, 0, stream>>>(
        memory, U_, Wm, U_, keys, U_, U_);
    // t=0 z-partials
    zgemm_partial<<<dim3(64, 4), 256, 0, stream>>>(h0, U_, Uh, zp);
    // Wo -> transposed bf16
    transpose_wo<<<dim3(VP_ / 64, 1024 / 64), 256, 0, stream>>>(Wo, wo_t);

    // ---- persistent recurrent loop ----
    decoder_loop11<<<256, 512, 0, stream>>>(
        zemb, Wcomb, keys, memory, c0, hcbuf, zp, hc_all, flags);

    // ---- post-loop ----
    // abf = bf16(hc_all @ Wa)  (split-MFMA, direct bf16 out; Wcomb dead)
    gemm_mfma_split<1><<<dim3(8, 25), 256, 0, stream>>>(
        hc_all, 2048, Wa, U_, (float*)abf, U_, 2048);
    // out = abf @ wo_t^T + bo  (double-buffered MFMA)
    gemm_wo_mfma3<<<dim3(VP_ / 128, 25), 256, 0, stream>>>(abf, wo_t, bo, out);
}